// Round 20
// baseline (1725.282 us; speedup 1.0000x reference)
//
#include <hip/hip_runtime.h>
#include <hip/hip_bf16.h>
#include <cmath>

#define C_IN 128
#define NKEY 32
#define N_H 4
#define D_H 32
#define C_BEV 256
#define H_Y 180
#define W_X 180

__device__ __forceinline__ float gelu_exact(float x) {
    return 0.5f * x * (1.0f + erff(x * 0.7071067811865475f));
}
__device__ __forceinline__ float dot4(float4 a, float4 b) {
    return a.x * b.x + a.y * b.y + a.z * b.z + a.w * b.w;
}

// ---- inv[cell] = m  (inv pre-memset to -1)
__global__ void build_inv(const int* __restrict__ ni, int* __restrict__ inv, int M) {
    const int m = blockIdx.x * 256 + threadIdx.x;
    if (m < M) {
        const int b = ni[m*4+0], y = ni[m*4+2], x = ni[m*4+3];
        inv[(b * H_Y + y) * W_X + x] = m;
    }
}

// ---- compact bev -> pack[m][0:256] contiguous (verified R8/R13)
__global__ __launch_bounds__(256) void compact_bev(
    const float* __restrict__ bev, const int* __restrict__ inv,
    float* __restrict__ pack)
{
    const int bid = blockIdx.x;
    const int xr = bid % 12;
    const int y  = (bid / 12) % H_Y;
    const int b  = bid / (12 * H_Y);
    const int x0 = xr * 16;
    const int width = (x0 + 16 <= W_X) ? 16 : (W_X - x0);
    const int tid = threadIdx.x;

    __shared__ float tile[16][257];

    const int xq = (tid & 3) * 4;
    #pragma unroll
    for (int p = 0; p < 4; ++p) {
        const int c = p * 64 + (tid >> 2);
        if (xq < width) {
            const float4 v = *(const float4*)(bev +
                (((size_t)b * C_BEV + c) * H_Y + y) * W_X + x0 + xq);
            tile[xq+0][c] = v.x; tile[xq+1][c] = v.y;
            tile[xq+2][c] = v.z; tile[xq+3][c] = v.w;
        }
    }
    __syncthreads();
    for (int xi = 0; xi < width; ++xi) {
        const int m = inv[(b * H_Y + y) * W_X + x0 + xi];
        if (m >= 0) pack[(size_t)m * C_BEV + tid] = tile[xi][tid];
    }
}

// ---- transposed write-out (R19): stage feat rows coalesced, write 64B lines.
__global__ __launch_bounds__(256) void write_out_t(
    const int* __restrict__ inv, const float* __restrict__ featbuf,
    float* __restrict__ out)
{
    const int bid = blockIdx.x;
    const int xr = bid % 12;
    const int y  = (bid / 12) % H_Y;
    const int b  = bid / (12 * H_Y);
    const int x0 = xr * 16;
    const int width = (x0 + 16 <= W_X) ? 16 : (W_X - x0);
    const int tid = threadIdx.x;

    __shared__ float tile[16][C_IN + 1];
    __shared__ int m16[16];

    if (tid < 16) m16[tid] = (tid < width) ? inv[(b * H_Y + y) * W_X + x0 + tid] : -1;
    __syncthreads();

    #pragma unroll
    for (int pass = 0; pass < 8; ++pass) {
        const int xi = pass * 2 + (tid >> 7);
        const int c  = tid & 127;
        const int m  = m16[xi];
        tile[xi][c] = (m >= 0) ? featbuf[(size_t)m * C_IN + c] : 0.0f;
    }
    __syncthreads();

    #pragma unroll
    for (int pass = 0; pass < 8; ++pass) {
        const int c  = pass * 16 + (tid >> 4);
        const int xi = tid & 15;
        if (xi < width)
            out[(((size_t)b * C_IN + c) * H_Y + y) * W_X + x0 + xi] = tile[xi][c];
    }
}

// ---- fused pre-attention: 8 queries / 1024-thread block, coalesced wave-GEMVs.
__global__ __launch_bounds__(1024) void k_pre(
    float* __restrict__ pack, const float* __restrict__ w_bev,
    const float* __restrict__ b_bev, const float* __restrict__ g_q,
    const float* __restrict__ be_q, const float* __restrict__ w_in,
    const float* __restrict__ b_in, float* __restrict__ sc_g, const int M)
{
    __shared__ float bevl[8][C_BEV];
    __shared__ float scl[8][C_IN];
    __shared__ float qlnl[8][C_IN];
    const int tid = threadIdx.x;
    const int m8 = blockIdx.x * 8;
    int mI[8];
    #pragma unroll
    for (int q = 0; q < 8; ++q) mI[q] = (m8 + q < M) ? (m8 + q) : (M - 1);
    const int wave = tid >> 6, lane = tid & 63;    // 16 waves

    #pragma unroll
    for (int i = tid; i < 8 * C_BEV; i += 1024) {
        const int q = i >> 8, k = i & 255;
        bevl[q][k] = pack[(size_t)mI[q] * C_BEV + k];
    }
    __syncthreads();

    // sc: wave-per-row GEMV, K=256 (1024 rows over 16 waves)
    #pragma unroll 4
    for (int t = wave; t < 1024; t += 16) {
        const int q = t >> 7, c = t & 127;
        const float4 w4 = ((const float4*)(w_bev + (size_t)c * C_BEV))[lane];
        const float4 b4 = ((const float4*)&bevl[q][0])[lane];
        float a = dot4(w4, b4);
        a += __shfl_xor(a, 1);  a += __shfl_xor(a, 2);  a += __shfl_xor(a, 4);
        a += __shfl_xor(a, 8);  a += __shfl_xor(a, 16); a += __shfl_xor(a, 32);
        if (lane == 0) {
            const float v = gelu_exact(a + b_bev[c]);
            scl[q][c] = v;
            if (m8 + q < M) sc_g[(size_t)mI[q] * C_IN + c] = v;
        }
    }
    __syncthreads();

    // qln = LN(sc): wave-pair per query (16 waves -> 8 queries)
    {
        const int q = wave >> 1;
        const float v0 = scl[q][lane], v1 = scl[q][lane + 64];
        float s = v0 + v1;
        #pragma unroll
        for (int o = 32; o >= 1; o >>= 1) s += __shfl_xor(s, o);
        const float mean = s * (1.0f / 128.0f);
        const float d0 = v0 - mean, d1 = v1 - mean;
        float vv = d0 * d0 + d1 * d1;
        #pragma unroll
        for (int o = 32; o >= 1; o >>= 1) vv += __shfl_xor(vv, o);
        const float rs = rsqrtf(vv * (1.0f / 128.0f) + 1e-5f);
        const int idx = lane + (wave & 1) * 64;
        const float myv = (wave & 1) ? v1 : v0;
        qlnl[q][idx] = (myv - mean) * rs * g_q[idx] + be_q[idx];
    }
    __syncthreads();

    // qh: half-wave-per-row GEMV, K=128 (1024 rows)
    #pragma unroll 4
    for (int t = wave; t < 512; t += 16) {
        const int row = t * 2 + (lane >> 5);     // 0..1023
        const int q = row >> 7, c = row & 127;
        const float4 w4 = ((const float4*)(w_in + (size_t)c * C_IN))[lane & 31];
        const float4 x4 = ((const float4*)&qlnl[q][0])[lane & 31];
        float a = dot4(w4, x4);
        a += __shfl_xor(a, 1); a += __shfl_xor(a, 2); a += __shfl_xor(a, 4);
        a += __shfl_xor(a, 8); a += __shfl_xor(a, 16);
        if ((lane & 31) == 0 && (m8 + q) < M)
            pack[(size_t)mI[q] * C_BEV + c] = a + b_in[c];
    }
}

// ---- attention kernel: 4 queries / 1024-thread block. kf in f32.
__global__ __launch_bounds__(1024) void k_attn(
    const float* __restrict__ vf, const int* __restrict__ spi,
    const int* __restrict__ ni, const int* __restrict__ kidx,
    float* __restrict__ pack,
    const float* __restrict__ w_pos, const float* __restrict__ b_pos,
    const float* __restrict__ g_k, const float* __restrict__ be_k,
    const float* __restrict__ w_in, const float* __restrict__ b_in,
    const int M)
{
    const int tid = threadIdx.x;
    const int m4 = blockIdx.x * 4;
    int mI[4];
    #pragma unroll
    for (int q = 0; q < 4; ++q) mI[q] = (m4 + q < M) ? (m4 + q) : (M - 1);

    __shared__ float kf32[4 * NKEY][C_IN + 4];   // 128 rows, 67.6 KB
    __shared__ float qhs[4 * C_IN];
    __shared__ float tk[4 * 4 * C_IN];
    __shared__ float attnw[4 * 4 * NKEY];
    __shared__ int   kmsk[4 * NKEY];

    // ---- P1: 128 key rows x 8 threads: gather + posemb GELU + LN_k -> kf32
    {
        const int kk = tid >> 3;          // 0..127
        const int qk = kk >> 5;           // 0..3
        const int g  = tid & 7;
        const int c0 = g * 16;
        const int mq = mI[qk];
        const int nxk = ni[mq*4+3], nyk = ni[mq*4+2];
        const float qxk = (nxk + 0.5f) * (150.4f / 180.0f) - 75.2f;
        const float qyk = (nyk + 0.5f) * (150.4f / 180.0f) - 75.2f;

        const int kv = kidx[mq * NKEY + (kk & 31)];
        if (g == 0) kmsk[kk] = (kv < 0) ? 1 : 0;
        const int safe = (kv < 0) ? 0 : kv;
        const int sz = spi[safe * 4 + 1];
        const int sy = spi[safe * 4 + 2];
        const int sx = spi[safe * 4 + 3];
        const float cx = (sx + 0.5f) * (150.4f / 1440.0f) - 75.2f - qxk;
        const float cy = (sy + 0.5f) * (150.4f / 1440.0f) - 75.2f - qyk;
        const float cz = (sz + 0.5f) * (6.0f / 40.0f)     - 2.0f  - 1.0f;

        float v[16];
        const float4* src = (const float4*)(vf + (size_t)safe * C_IN + c0);
        #pragma unroll
        for (int j = 0; j < 4; ++j) {
            float4 t = src[j];
            v[j*4+0] = t.x; v[j*4+1] = t.y; v[j*4+2] = t.z; v[j*4+3] = t.w;
        }
        #pragma unroll
        for (int j = 0; j < 16; ++j) {
            const int c = c0 + j;
            float e = cx * w_pos[c*3+0] + cy * w_pos[c*3+1] + cz * w_pos[c*3+2] + b_pos[c];
            v[j] += gelu_exact(e);
        }
        float s = 0.f;
        #pragma unroll
        for (int j = 0; j < 16; ++j) s += v[j];
        s += __shfl_xor(s, 1); s += __shfl_xor(s, 2); s += __shfl_xor(s, 4);
        const float mean = s * (1.0f / 128.0f);
        float vv = 0.f;
        #pragma unroll
        for (int j = 0; j < 16; ++j) { float d = v[j] - mean; vv += d * d; }
        vv += __shfl_xor(vv, 1); vv += __shfl_xor(vv, 2); vv += __shfl_xor(vv, 4);
        const float rs = rsqrtf(vv * (1.0f / 128.0f) + 1e-5f);
        float4* drow = (float4*)(&kf32[kk][c0]);
        #pragma unroll
        for (int j4 = 0; j4 < 4; ++j4) {
            float4 o;
            o.x = (v[j4*4+0] - mean) * rs * g_k[c0+j4*4+0] + be_k[c0+j4*4+0];
            o.y = (v[j4*4+1] - mean) * rs * g_k[c0+j4*4+1] + be_k[c0+j4*4+1];
            o.z = (v[j4*4+2] - mean) * rs * g_k[c0+j4*4+2] + be_k[c0+j4*4+2];
            o.w = (v[j4*4+3] - mean) * rs * g_k[c0+j4*4+3] + be_k[c0+j4*4+3];
            drow[j4] = o;
        }
    }

    // stage qh from pack[m][0:128]
    if (tid < 512) {
        const int q = tid >> 7, idx = tid & 127;
        qhs[q * 128 + idx] = pack[(size_t)mI[q] * C_BEV + idx];
    }
    __syncthreads();

    // ---- t[h] = qh_h @ wk_h  (q = tid>>8 covers 0..3)
    {
        const int q = tid >> 8, r = tid & 255;
        const int c = r & 127, h2 = r >> 7;
        #pragma unroll
        for (int hi = 0; hi < 2; ++hi) {
            const int hh = h2 + 2 * hi;
            float acc = 0.f;
            #pragma unroll
            for (int d = 0; d < D_H; ++d)
                acc += qhs[q*128 + hh*D_H + d] * w_in[(size_t)(C_IN + hh*D_H + d) * C_IN + c];
            tk[(q*4 + hh)*128 + c] = acc;
        }
    }
    __syncthreads();

    // ---- logits + masked softmax: all 1024 threads, f32 float4 dots
    {
        const int q = tid >> 8, r = tid & 255;
        const int h = r >> 6, half = (r >> 5) & 1, p = r & 31;
        float tbv = qhs[q*128 + h*D_H + p] * b_in[C_IN + h*D_H + p];
        #pragma unroll
        for (int o = 16; o >= 1; o >>= 1) tbv += __shfl_xor(tbv, o);
        const float4* tr = (const float4*)&tk[(q*4 + h)*128 + half*64];
        const float4* kr = (const float4*)&kf32[q*NKEY + p][half*64];
        float d = 0.f;
        #pragma unroll
        for (int c4 = 0; c4 < 16; ++c4) d += dot4(tr[c4], kr[c4]);
        d += __shfl_xor(d, 32);
        const int msk = kmsk[q*NKEY + p];
        float logit = msk ? -3.0e38f : (d + tbv) * 0.17677669529663687f;
        float mx = logit;
        #pragma unroll
        for (int o = 16; o >= 1; o >>= 1) mx = fmaxf(mx, __shfl_xor(mx, o));
        const float e = msk ? 0.0f : expf(logit - mx);
        float ssum = e;
        #pragma unroll
        for (int o = 16; o >= 1; o >>= 1) ssum += __shfl_xor(ssum, o);
        if (half == 0) attnw[(q*4 + h)*32 + p] = e / ssum;
    }
    __syncthreads();

    // ---- kbar[h] = sum_p attn[h,p] k[p]  (overwrites tk)
    {
        const int q = tid >> 8, r = tid & 255;
        const int c = r & 127, h2 = r >> 7;
        #pragma unroll
        for (int hi = 0; hi < 2; ++hi) {
            const int hh = h2 + 2 * hi;
            float acc = 0.f;
            #pragma unroll
            for (int p = 0; p < NKEY; ++p)
                acc += attnw[(q*4 + hh)*32 + p] * kf32[q*NKEY + p][c];
            tk[(q*4 + hh)*128 + c] = acc;
        }
    }
    __syncthreads();

    // ---- av: half-wave-per-row coalesced GEMV over w_in rows [256,384)
    {
        const int wave = tid >> 6, lane = tid & 63;   // 16 waves
        #pragma unroll 4
        for (int t = wave; t < 256; t += 16) {
            const int row = t * 2 + (lane >> 5);   // 0..511
            const int q = row >> 7, j = row & 127;
            const int h = j >> 5;
            const float4 w4 = ((const float4*)(w_in + (size_t)(2*C_IN + j) * C_IN))[lane & 31];
            const float4 k4 = ((const float4*)&tk[(q*4 + h)*128])[lane & 31];
            float a = dot4(w4, k4);
            a += __shfl_xor(a, 1); a += __shfl_xor(a, 2); a += __shfl_xor(a, 4);
            a += __shfl_xor(a, 8); a += __shfl_xor(a, 16);
            if ((lane & 31) == 0 && (m4 + q) < M)
                pack[(size_t)mI[q] * C_BEV + C_IN + j] = a + b_in[2*C_IN + j];
        }
    }
}

// ---- fused post-attention: 8 queries / 1024-thread block.
__global__ __launch_bounds__(1024) void k_post(
    const float* __restrict__ pack,
    const float* __restrict__ w_out, const float* __restrict__ b_out,
    const float* __restrict__ g_f, const float* __restrict__ be_f,
    const float* __restrict__ w_fc1, const float* __restrict__ b_fc1,
    const float* __restrict__ w_fc2, const float* __restrict__ b_fc2,
    float* __restrict__ scfeat, const int M)
{
    __shared__ float avl[8][C_IN];
    __shared__ float sclp[8][C_IN];
    __shared__ float xfl[8][C_IN];
    __shared__ float ylnl[8][C_IN];
    __shared__ float h1l[8][C_IN];
    const int tid = threadIdx.x;
    const int m8 = blockIdx.x * 8;
    int mI[8];
    #pragma unroll
    for (int q = 0; q < 8; ++q) mI[q] = (m8 + q < M) ? (m8 + q) : (M - 1);
    const int wave = tid >> 6, lane = tid & 63;   // 16 waves

    {
        const int q = tid >> 7, i = tid & 127;    // 8 queries x 128
        avl[q][i]  = pack[(size_t)mI[q] * C_BEV + C_IN + i];
        sclp[q][i] = scfeat[(size_t)mI[q] * C_IN + i];
    }
    __syncthreads();

    // xf = av @ w_out^T + b_out + sc  (1024 rows)
    #pragma unroll 4
    for (int t = wave; t < 512; t += 16) {
        const int row = t * 2 + (lane >> 5);
        const int q = row >> 7, c = row & 127;
        const float4 w4 = ((const float4*)(w_out + (size_t)c * C_IN))[lane & 31];
        const float4 a4 = ((const float4*)&avl[q][0])[lane & 31];
        float a = dot4(w4, a4);
        a += __shfl_xor(a, 1); a += __shfl_xor(a, 2); a += __shfl_xor(a, 4);
        a += __shfl_xor(a, 8); a += __shfl_xor(a, 16);
        if ((lane & 31) == 0) xfl[q][c] = a + b_out[c] + sclp[q][c];
    }
    __syncthreads();

    // yln = LN(xf): wave-pair per query
    {
        const int q = wave >> 1;
        const float v0 = xfl[q][lane], v1 = xfl[q][lane + 64];
        float s = v0 + v1;
        #pragma unroll
        for (int o = 32; o >= 1; o >>= 1) s += __shfl_xor(s, o);
        const float mean = s * (1.0f / 128.0f);
        const float d0 = v0 - mean, d1 = v1 - mean;
        float vv = d0 * d0 + d1 * d1;
        #pragma unroll
        for (int o = 32; o >= 1; o >>= 1) vv += __shfl_xor(vv, o);
        const float rs = rsqrtf(vv * (1.0f / 128.0f) + 1e-5f);
        const int idx = lane + (wave & 1) * 64;
        const float myv = (wave & 1) ? v1 : v0;
        ylnl[q][idx] = (myv - mean) * rs * g_f[idx] + be_f[idx];
    }
    __syncthreads();

    // h1 = gelu(yln @ w_fc1^T + b_fc1)
    #pragma unroll 4
    for (int t = wave; t < 512; t += 16) {
        const int row = t * 2 + (lane >> 5);
        const int q = row >> 7, c = row & 127;
        const float4 w4 = ((const float4*)(w_fc1 + (size_t)c * C_IN))[lane & 31];
        const float4 y4 = ((const float4*)&ylnl[q][0])[lane & 31];
        float a = dot4(w4, y4);
        a += __shfl_xor(a, 1); a += __shfl_xor(a, 2); a += __shfl_xor(a, 4);
        a += __shfl_xor(a, 8); a += __shfl_xor(a, 16);
        if ((lane & 31) == 0) h1l[q][c] = gelu_exact(a + b_fc1[c]);
    }
    __syncthreads();

    // feat = h1 @ w_fc2^T + b_fc2 + xf -> scfeat in-place
    #pragma unroll 4
    for (int t = wave; t < 512; t += 16) {
        const int row = t * 2 + (lane >> 5);
        const int q = row >> 7, c = row & 127;
        const float4 w4 = ((const float4*)(w_fc2 + (size_t)c * C_IN))[lane & 31];
        const float4 h4 = ((const float4*)&h1l[q][0])[lane & 31];
        float a = dot4(w4, h4);
        a += __shfl_xor(a, 1); a += __shfl_xor(a, 2); a += __shfl_xor(a, 4);
        a += __shfl_xor(a, 8); a += __shfl_xor(a, 16);
        if ((lane & 31) == 0 && (m8 + q) < M)
            scfeat[(size_t)mI[q] * C_IN + c] = a + b_fc2[c] + xfl[q][c];
    }
}

extern "C" void kernel_launch(void* const* d_in, const int* in_sizes, int n_in,
                              void* d_out, int out_size, void* d_ws, size_t ws_size,
                              hipStream_t stream) {
    const float* vf    = (const float*)d_in[0];
    const int*   spi   = (const int*)  d_in[1];
    const int*   ni    = (const int*)  d_in[2];
    const int*   kidx  = (const int*)  d_in[3];
    const float* bev   = (const float*)d_in[4];
    const float* w_pos = (const float*)d_in[5];
    const float* b_pos = (const float*)d_in[6];
    const float* w_bev = (const float*)d_in[7];
    const float* b_bev = (const float*)d_in[8];
    const float* g_q   = (const float*)d_in[9];
    const float* be_q  = (const float*)d_in[10];
    const float* g_k   = (const float*)d_in[11];
    const float* be_k  = (const float*)d_in[12];
    const float* g_f   = (const float*)d_in[13];
    const float* be_f  = (const float*)d_in[14];
    const float* w_in  = (const float*)d_in[15];
    const float* b_in  = (const float*)d_in[16];
    const float* w_out = (const float*)d_in[17];
    const float* b_out = (const float*)d_in[18];
    const float* w_fc1 = (const float*)d_in[19];
    const float* b_fc1 = (const float*)d_in[20];
    const float* w_fc2 = (const float*)d_in[21];
    const float* b_fc2 = (const float*)d_in[22];
    float* out = (float*)d_out;

    const int M = in_sizes[3] / NKEY;

    char* ws = (char*)d_ws;
    const size_t MiB = 1u << 20;
    int*   inv    = (int*)ws;
    float* pack   = (float*)(ws + 2 * MiB);
    float* scfeat = (float*)(ws + 32 * MiB);

    hipMemsetAsync(inv, 0xFF, (size_t)4 * H_Y * W_X * sizeof(int), stream);
    build_inv<<<(M + 255) / 256, 256, 0, stream>>>(ni, inv, M);
    compact_bev<<<4 * H_Y * 12, 256, 0, stream>>>(bev, inv, pack);

    k_pre<<<(M + 7) / 8, 1024, 0, stream>>>(pack, w_bev, b_bev, g_q, be_q, w_in, b_in, scfeat, M);
    k_attn<<<(M + 3) / 4, 1024, 0, stream>>>(vf, spi, ni, kidx, pack, w_pos, b_pos,
                                             g_k, be_k, w_in, b_in, M);
    k_post<<<(M + 7) / 8, 1024, 0, stream>>>(pack, w_out, b_out, g_f, be_f,
                                             w_fc1, b_fc1, w_fc2, b_fc2, scfeat, M);

    write_out_t<<<4 * H_Y * 12, 256, 0, stream>>>(inv, scfeat, out);
}

// Round 21
// 724.542 us; speedup vs baseline: 2.3812x; 2.3812x over previous
//
#include <hip/hip_runtime.h>
#include <hip/hip_bf16.h>
#include <cmath>

#define C_IN 128
#define NKEY 32
#define N_H 4
#define D_H 32
#define C_BEV 256
#define H_Y 180
#define W_X 180

typedef __attribute__((ext_vector_type(8))) short short8;
typedef __attribute__((ext_vector_type(4))) float f32x4;

__device__ __forceinline__ float gelu_exact(float x) {
    return 0.5f * x * (1.0f + erff(x * 0.7071067811865475f));
}
__device__ __forceinline__ float dot4(float4 a, float4 b) {
    return a.x * b.x + a.y * b.y + a.z * b.z + a.w * b.w;
}
__device__ __forceinline__ float bf2f(ushort u) {
    union { unsigned int i; float f; } c; c.i = ((unsigned int)u) << 16; return c.f;
}
__device__ __forceinline__ ushort f2bf(float x) {
    __hip_bfloat16 h = __float2bfloat16(x);
    return *reinterpret_cast<ushort*>(&h);
}

// ---- one-time: convert f32 weight [OUT][K] to bf16 in MFMA fragment order:
//   dst[(((ct*NK + kt)*64 + lane))*8 + j] = bf16(src[(ct*16 + lane&15)][kt*32 + (lane>>4)*8 + j])
__global__ void conv_swz(const float* __restrict__ src, ushort* __restrict__ dst,
                         int K, int total) {
    const int idx = blockIdx.x * 256 + threadIdx.x;
    if (idx < total) {
        const int j = idx & 7;
        const int t8 = idx >> 3;
        const int lane = t8 & 63;
        const int tile = t8 >> 6;
        const int NK = K >> 5;
        const int kt = tile % NK, ct = tile / NK;
        const int row = ct * 16 + (lane & 15);
        const int k = kt * 32 + (lane >> 4) * 8 + j;
        dst[idx] = f2bf(src[(size_t)row * K + k]);
    }
}

// ---- inv[cell] = m  (inv pre-memset to -1)
__global__ void build_inv(const int* __restrict__ ni, int* __restrict__ inv, int M) {
    const int m = blockIdx.x * 256 + threadIdx.x;
    if (m < M) {
        const int b = ni[m*4+0], y = ni[m*4+2], x = ni[m*4+3];
        inv[(b * H_Y + y) * W_X + x] = m;
    }
}

// ---- compact bev -> pack[m][0:256] contiguous (verified R8/R13)
__global__ __launch_bounds__(256) void compact_bev(
    const float* __restrict__ bev, const int* __restrict__ inv,
    float* __restrict__ pack)
{
    const int bid = blockIdx.x;
    const int xr = bid % 12;
    const int y  = (bid / 12) % H_Y;
    const int b  = bid / (12 * H_Y);
    const int x0 = xr * 16;
    const int width = (x0 + 16 <= W_X) ? 16 : (W_X - x0);
    const int tid = threadIdx.x;

    __shared__ float tile[16][257];

    const int xq = (tid & 3) * 4;
    #pragma unroll
    for (int p = 0; p < 4; ++p) {
        const int c = p * 64 + (tid >> 2);
        if (xq < width) {
            const float4 v = *(const float4*)(bev +
                (((size_t)b * C_BEV + c) * H_Y + y) * W_X + x0 + xq);
            tile[xq+0][c] = v.x; tile[xq+1][c] = v.y;
            tile[xq+2][c] = v.z; tile[xq+3][c] = v.w;
        }
    }
    __syncthreads();
    for (int xi = 0; xi < width; ++xi) {
        const int m = inv[(b * H_Y + y) * W_X + x0 + xi];
        if (m >= 0) pack[(size_t)m * C_BEV + tid] = tile[xi][tid];
    }
}

// ---- transposed write-out (verified R19)
__global__ __launch_bounds__(256) void write_out_t(
    const int* __restrict__ inv, const float* __restrict__ featbuf,
    float* __restrict__ out)
{
    const int bid = blockIdx.x;
    const int xr = bid % 12;
    const int y  = (bid / 12) % H_Y;
    const int b  = bid / (12 * H_Y);
    const int x0 = xr * 16;
    const int width = (x0 + 16 <= W_X) ? 16 : (W_X - x0);
    const int tid = threadIdx.x;

    __shared__ float tile[16][C_IN + 1];
    __shared__ int m16[16];

    if (tid < 16) m16[tid] = (tid < width) ? inv[(b * H_Y + y) * W_X + x0 + tid] : -1;
    __syncthreads();

    #pragma unroll
    for (int pass = 0; pass < 8; ++pass) {
        const int xi = pass * 2 + (tid >> 7);
        const int c  = tid & 127;
        const int m  = m16[xi];
        tile[xi][c] = (m >= 0) ? featbuf[(size_t)m * C_IN + c] : 0.0f;
    }
    __syncthreads();

    #pragma unroll
    for (int pass = 0; pass < 8; ++pass) {
        const int c  = pass * 16 + (tid >> 4);
        const int xi = tid & 15;
        if (xi < width)
            out[(((size_t)b * C_IN + c) * H_Y + y) * W_X + x0 + xi] = tile[xi][c];
    }
}

// ---- MFMA pre-attention: 16 queries / 256-thread block (4 waves).
//   sc = gelu(bev @ w_bev^T + b); qln = LN(sc); qh = qln @ wq^T + bq -> pack[m][0:128]
__global__ __launch_bounds__(256) void k_pre(
    float* __restrict__ pack, const ushort* __restrict__ wbev_s,
    const float* __restrict__ b_bev, const float* __restrict__ g_q,
    const float* __restrict__ be_q, const ushort* __restrict__ wq_s,
    const float* __restrict__ b_in, float* __restrict__ sc_g, const int M)
{
    __shared__ ushort bevl16[16][C_BEV + 8];   // A for sc GEMM (bf16)
    __shared__ float  scl[16][C_IN];           // sc, later qh
    __shared__ ushort qlnl16[16][C_IN + 8];    // A for qh GEMM
    const int tid = threadIdx.x;
    const int m16 = blockIdx.x * 16;
    const int wave = tid >> 6, lane = tid & 63;
    const int llo = lane & 15, lhi = lane >> 4;
    const int qs = tid >> 4, seg = tid & 15;
    int mq = m16 + qs; if (mq >= M) mq = M - 1;

    // stage bev -> bf16 (coalesced 16 floats/thread)
    {
        const float4* srcp = (const float4*)(pack + (size_t)mq * C_BEV + seg * 16);
        ushort tmp[16];
        #pragma unroll
        for (int j4 = 0; j4 < 4; ++j4) {
            const float4 v = srcp[j4];
            tmp[j4*4+0] = f2bf(v.x); tmp[j4*4+1] = f2bf(v.y);
            tmp[j4*4+2] = f2bf(v.z); tmp[j4*4+3] = f2bf(v.w);
        }
        short8* d = (short8*)&bevl16[qs][seg * 16];
        d[0] = *(short8*)&tmp[0];
        d[1] = *(short8*)&tmp[8];
    }
    __syncthreads();                                  // B1

    // sc GEMM: 16x128x256; wave handles col-tiles {wave, wave+4}
    {
        f32x4 acc0 = {0.f,0.f,0.f,0.f}, acc1 = {0.f,0.f,0.f,0.f};
        #pragma unroll
        for (int kt = 0; kt < 8; ++kt) {
            const short8 a = *(const short8*)&bevl16[llo][kt*32 + lhi*8];
            const short8 b0 = *(const short8*)&wbev_s[(size_t)(((wave    )*8 + kt)*64 + lane)*8];
            const short8 b1 = *(const short8*)&wbev_s[(size_t)(((wave + 4)*8 + kt)*64 + lane)*8];
            acc0 = __builtin_amdgcn_mfma_f32_16x16x32_bf16(a, b0, acc0, 0, 0, 0);
            acc1 = __builtin_amdgcn_mfma_f32_16x16x32_bf16(a, b1, acc1, 0, 0, 0);
        }
        #pragma unroll
        for (int qe = 0; qe < 4; ++qe) {
            const int row = lhi * 4 + qe;
            const int c0 = wave * 16 + llo, c1 = (wave + 4) * 16 + llo;
            scl[row][c0] = gelu_exact(acc0[qe] + b_bev[c0]);
            scl[row][c1] = gelu_exact(acc1[qe] + b_bev[c1]);
        }
    }
    __syncthreads();                                  // B2

    // sc_g coalesced write + LN -> qlnl16 (16 threads per query)
    {
        float* dst = sc_g + (size_t)mq * C_IN + seg * 8;
        float v[8];
        #pragma unroll
        for (int j = 0; j < 8; ++j) v[j] = scl[qs][seg * 8 + j];
        *(float4*)&dst[0] = make_float4(v[0], v[1], v[2], v[3]);
        *(float4*)&dst[4] = make_float4(v[4], v[5], v[6], v[7]);

        float s = 0.f;
        #pragma unroll
        for (int j = 0; j < 8; ++j) s += v[j];
        s += __shfl_xor(s, 1); s += __shfl_xor(s, 2);
        s += __shfl_xor(s, 4); s += __shfl_xor(s, 8);
        const float mean = s * (1.0f / 128.0f);
        float vv = 0.f;
        #pragma unroll
        for (int j = 0; j < 8; ++j) { const float d = v[j] - mean; vv += d * d; }
        vv += __shfl_xor(vv, 1); vv += __shfl_xor(vv, 2);
        vv += __shfl_xor(vv, 4); vv += __shfl_xor(vv, 8);
        const float rs = rsqrtf(vv * (1.0f / 128.0f) + 1e-5f);
        #pragma unroll
        for (int j = 0; j < 8; ++j) {
            const int c = seg * 8 + j;
            qlnl16[qs][c] = f2bf((v[j] - mean) * rs * g_q[c] + be_q[c]);
        }
    }
    __syncthreads();                                  // B3

    // qh GEMM: 16x128x128 -> scl (reuse)
    {
        f32x4 acc0 = {0.f,0.f,0.f,0.f}, acc1 = {0.f,0.f,0.f,0.f};
        #pragma unroll
        for (int kt = 0; kt < 4; ++kt) {
            const short8 a = *(const short8*)&qlnl16[llo][kt*32 + lhi*8];
            const short8 b0 = *(const short8*)&wq_s[(size_t)(((wave    )*4 + kt)*64 + lane)*8];
            const short8 b1 = *(const short8*)&wq_s[(size_t)(((wave + 4)*4 + kt)*64 + lane)*8];
            acc0 = __builtin_amdgcn_mfma_f32_16x16x32_bf16(a, b0, acc0, 0, 0, 0);
            acc1 = __builtin_amdgcn_mfma_f32_16x16x32_bf16(a, b1, acc1, 0, 0, 0);
        }
        #pragma unroll
        for (int qe = 0; qe < 4; ++qe) {
            const int row = lhi * 4 + qe;
            const int c0 = wave * 16 + llo, c1 = (wave + 4) * 16 + llo;
            scl[row][c0] = acc0[qe] + b_in[c0];
            scl[row][c1] = acc1[qe] + b_in[c1];
        }
    }
    __syncthreads();                                  // B4

    // qh coalesced write -> pack[m][0:128]
    {
        float* dst = pack + (size_t)mq * C_BEV + seg * 8;
        *(float4*)&dst[0] = make_float4(scl[qs][seg*8+0], scl[qs][seg*8+1],
                                        scl[qs][seg*8+2], scl[qs][seg*8+3]);
        *(float4*)&dst[4] = make_float4(scl[qs][seg*8+4], scl[qs][seg*8+5],
                                        scl[qs][seg*8+6], scl[qs][seg*8+7]);
    }
}

// ---- attention kernel (R18 verbatim — best measured 631 us)
__global__ __launch_bounds__(512) void k_attn(
    const float* __restrict__ vf, const int* __restrict__ spi,
    const int* __restrict__ ni, const int* __restrict__ kidx,
    float* __restrict__ pack,
    const float* __restrict__ w_pos, const float* __restrict__ b_pos,
    const float* __restrict__ g_k, const float* __restrict__ be_k,
    const float* __restrict__ w_in, const float* __restrict__ b_in,
    const int M)
{
    const int tid = threadIdx.x;
    const int m2 = blockIdx.x * 2;
    const int mA = m2;
    const int mB = (m2 + 1 < M) ? (m2 + 1) : (M - 1);

    __shared__ ushort kf16[64][C_IN + 8];
    __shared__ float qhs[2 * C_IN];
    __shared__ float tk[2 * 4 * C_IN];
    __shared__ float attnw[2 * 4 * NKEY];
    __shared__ int   kmsk[64];

    const int nxA = ni[mA*4+3], nyA = ni[mA*4+2];
    const int nxB = ni[mB*4+3], nyB = ni[mB*4+2];

    {
        const int kk = tid >> 3;
        const int qk = kk >> 5;
        const int g  = tid & 7;
        const int c0 = g * 16;
        const int mq = qk ? mB : mA;
        const int nxk = qk ? nxB : nxA, nyk = qk ? nyB : nyA;
        const float qxk = (nxk + 0.5f) * (150.4f / 180.0f) - 75.2f;
        const float qyk = (nyk + 0.5f) * (150.4f / 180.0f) - 75.2f;

        const int kv = kidx[mq * NKEY + (kk & 31)];
        if (g == 0) kmsk[kk] = (kv < 0) ? 1 : 0;
        const int safe = (kv < 0) ? 0 : kv;
        const int sz = spi[safe * 4 + 1];
        const int sy = spi[safe * 4 + 2];
        const int sx = spi[safe * 4 + 3];
        const float cx = (sx + 0.5f) * (150.4f / 1440.0f) - 75.2f - qxk;
        const float cy = (sy + 0.5f) * (150.4f / 1440.0f) - 75.2f - qyk;
        const float cz = (sz + 0.5f) * (6.0f / 40.0f)     - 2.0f  - 1.0f;

        float v[16];
        const float4* src = (const float4*)(vf + (size_t)safe * C_IN + c0);
        #pragma unroll
        for (int j = 0; j < 4; ++j) {
            float4 t = src[j];
            v[j*4+0] = t.x; v[j*4+1] = t.y; v[j*4+2] = t.z; v[j*4+3] = t.w;
        }
        #pragma unroll
        for (int j = 0; j < 16; ++j) {
            const int c = c0 + j;
            float e = cx * w_pos[c*3+0] + cy * w_pos[c*3+1] + cz * w_pos[c*3+2] + b_pos[c];
            v[j] += gelu_exact(e);
        }
        float s = 0.f;
        #pragma unroll
        for (int j = 0; j < 16; ++j) s += v[j];
        s += __shfl_xor(s, 1); s += __shfl_xor(s, 2); s += __shfl_xor(s, 4);
        const float mean = s * (1.0f / 128.0f);
        float vv = 0.f;
        #pragma unroll
        for (int j = 0; j < 16; ++j) { float d = v[j] - mean; vv += d * d; }
        vv += __shfl_xor(vv, 1); vv += __shfl_xor(vv, 2); vv += __shfl_xor(vv, 4);
        const float rs = rsqrtf(vv * (1.0f / 128.0f) + 1e-5f);
        ushort o[16];
        #pragma unroll
        for (int j = 0; j < 16; ++j) {
            const int c = c0 + j;
            o[j] = f2bf((v[j] - mean) * rs * g_k[c] + be_k[c]);
        }
        short8* drow = (short8*)(&kf16[kk][c0]);
        drow[0] = *(short8*)&o[0];
        drow[1] = *(short8*)&o[8];
    }

    if (tid < 256) {
        const int q = tid >> 7, idx = tid & 127;
        qhs[q * 128 + idx] = pack[(size_t)(q ? mB : mA) * C_BEV + idx];
    }
    __syncthreads();

    {
        const int q = tid >> 8, r = tid & 255;
        const int c = r & 127, h2 = r >> 7;
        #pragma unroll
        for (int hi = 0; hi < 2; ++hi) {
            const int hh = h2 + 2 * hi;
            float acc = 0.f;
            #pragma unroll
            for (int d = 0; d < D_H; ++d)
                acc += qhs[q*128 + hh*D_H + d] * w_in[(size_t)(C_IN + hh*D_H + d) * C_IN + c];
            tk[(q*4 + hh)*128 + c] = acc;
        }
    }
    __syncthreads();

    {
        const int q = tid >> 8, r = tid & 255;
        const int h = r >> 6, half = (r >> 5) & 1, p = r & 31;
        float tbv = qhs[q*128 + h*D_H + p] * b_in[C_IN + h*D_H + p];
        #pragma unroll
        for (int o = 16; o >= 1; o >>= 1) tbv += __shfl_xor(tbv, o);
        const float* tr = &tk[(q*4 + h)*128 + half*64];
        const ushort* kr = &kf16[q*NKEY + p][half*64];
        float d = 0.f;
        #pragma unroll
        for (int c2 = 0; c2 < 32; ++c2) {
            const uint u = *(const uint*)&kr[c2*2];
            d += tr[c2*2]   * bf2f((ushort)(u & 0xffff));
            d += tr[c2*2+1] * bf2f((ushort)(u >> 16));
        }
        d += __shfl_xor(d, 32);
        const int msk = kmsk[q*NKEY + p];
        float logit = msk ? -3.0e38f : (d + tbv) * 0.17677669529663687f;
        float mx = logit;
        #pragma unroll
        for (int o = 16; o >= 1; o >>= 1) mx = fmaxf(mx, __shfl_xor(mx, o));
        const float e = msk ? 0.0f : expf(logit - mx);
        float ssum = e;
        #pragma unroll
        for (int o = 16; o >= 1; o >>= 1) ssum += __shfl_xor(ssum, o);
        if (half == 0) attnw[(q*4 + h)*32 + p] = e / ssum;
    }
    __syncthreads();

    {
        const int q = tid >> 8, r = tid & 255;
        const int c = r & 127, h2 = r >> 7;
        #pragma unroll
        for (int hi = 0; hi < 2; ++hi) {
            const int hh = h2 + 2 * hi;
            float acc = 0.f;
            #pragma unroll
            for (int p = 0; p < NKEY; ++p)
                acc += attnw[(q*4 + hh)*32 + p] * bf2f(kf16[q*NKEY + p][c]);
            tk[(q*4 + hh)*128 + c] = acc;
        }
    }
    __syncthreads();

    {
        const int wave = tid >> 6, lane = tid & 63;
        #pragma unroll 4
        for (int t = wave; t < 128; t += 8) {
            const int row = t * 2 + (lane >> 5);
            const int q = row >> 7, j = row & 127;
            const int h = j >> 5;
            const float4 w4 = ((const float4*)(w_in + (size_t)(2*C_IN + j) * C_IN))[lane & 31];
            const float4 k4 = ((const float4*)&tk[(q*4 + h)*128])[lane & 31];
            float a = dot4(w4, k4);
            a += __shfl_xor(a, 1); a += __shfl_xor(a, 2); a += __shfl_xor(a, 4);
            a += __shfl_xor(a, 8); a += __shfl_xor(a, 16);
            if ((lane & 31) == 0 && (m2 + q) < M)
                pack[(size_t)(q ? mB : mA) * C_BEV + C_IN + j] = a + b_in[2*C_IN + j];
        }
    }
}

// ---- MFMA post-attention: 16 queries / 256-thread block.
//   xf = av@w_out^T + b + sc; yln = LN(xf); h1 = gelu(yln@w_fc1^T+b);
//   feat = h1@w_fc2^T + b + xf -> scfeat in-place.
__global__ __launch_bounds__(256) void k_post(
    const float* __restrict__ pack,
    const ushort* __restrict__ wout_s, const float* __restrict__ b_out,
    const float* __restrict__ g_f, const float* __restrict__ be_f,
    const ushort* __restrict__ wfc1_s, const float* __restrict__ b_fc1,
    const ushort* __restrict__ wfc2_s, const float* __restrict__ b_fc2,
    float* __restrict__ scfeat, const int M)
{
    __shared__ ushort avl16[16][C_IN + 8];
    __shared__ float  sclp[16][C_IN];     // sc, then feat out
    __shared__ float  xfl[16][C_IN];
    __shared__ ushort ylnl16[16][C_IN + 8];
    __shared__ ushort h1l16[16][C_IN + 8];
    const int tid = threadIdx.x;
    const int m16 = blockIdx.x * 16;
    const int wave = tid >> 6, lane = tid & 63;
    const int llo = lane & 15, lhi = lane >> 4;
    const int qs = tid >> 4, seg = tid & 15;
    int mq = m16 + qs; if (mq >= M) mq = M - 1;

    // stage av (bf16) + sc (f32); 8 elems each per thread, coalesced
    {
        const float4* ap = (const float4*)(pack + (size_t)mq * C_BEV + C_IN + seg * 8);
        const float4 a0 = ap[0], a1 = ap[1];
        ushort tmp[8];
        tmp[0]=f2bf(a0.x); tmp[1]=f2bf(a0.y); tmp[2]=f2bf(a0.z); tmp[3]=f2bf(a0.w);
        tmp[4]=f2bf(a1.x); tmp[5]=f2bf(a1.y); tmp[6]=f2bf(a1.z); tmp[7]=f2bf(a1.w);
        *(short8*)&avl16[qs][seg * 8] = *(short8*)&tmp[0];
        const float4* sp = (const float4*)(scfeat + (size_t)mq * C_IN + seg * 8);
        *(float4*)&sclp[qs][seg * 8]     = sp[0];
        *(float4*)&sclp[qs][seg * 8 + 4] = sp[1];
    }
    __syncthreads();                                  // B1

    // xf GEMM: 16x128x128 + b_out + sc -> xfl
    {
        f32x4 acc0 = {0.f,0.f,0.f,0.f}, acc1 = {0.f,0.f,0.f,0.f};
        #pragma unroll
        for (int kt = 0; kt < 4; ++kt) {
            const short8 a = *(const short8*)&avl16[llo][kt*32 + lhi*8];
            const short8 b0 = *(const short8*)&wout_s[(size_t)(((wave    )*4 + kt)*64 + lane)*8];
            const short8 b1 = *(const short8*)&wout_s[(size_t)(((wave + 4)*4 + kt)*64 + lane)*8];
            acc0 = __builtin_amdgcn_mfma_f32_16x16x32_bf16(a, b0, acc0, 0, 0, 0);
            acc1 = __builtin_amdgcn_mfma_f32_16x16x32_bf16(a, b1, acc1, 0, 0, 0);
        }
        #pragma unroll
        for (int qe = 0; qe < 4; ++qe) {
            const int row = lhi * 4 + qe;
            const int c0 = wave * 16 + llo, c1 = (wave + 4) * 16 + llo;
            xfl[row][c0] = acc0[qe] + b_out[c0] + sclp[row][c0];
            xfl[row][c1] = acc1[qe] + b_out[c1] + sclp[row][c1];
        }
    }
    __syncthreads();                                  // B2

    // LN(xf) -> ylnl16 (16 threads/query)
    {
        float v[8];
        #pragma unroll
        for (int j = 0; j < 8; ++j) v[j] = xfl[qs][seg * 8 + j];
        float s = 0.f;
        #pragma unroll
        for (int j = 0; j < 8; ++j) s += v[j];
        s += __shfl_xor(s, 1); s += __shfl_xor(s, 2);
        s += __shfl_xor(s, 4); s += __shfl_xor(s, 8);
        const float mean = s * (1.0f / 128.0f);
        float vv = 0.f;
        #pragma unroll
        for (int j = 0; j < 8; ++j) { const float d = v[j] - mean; vv += d * d; }
        vv += __shfl_xor(vv, 1); vv += __shfl_xor(vv, 2);
        vv += __shfl_xor(vv, 4); vv += __shfl_xor(vv, 8);
        const float rs = rsqrtf(vv * (1.0f / 128.0f) + 1e-5f);
        #pragma unroll
        for (int j = 0; j < 8; ++j) {
            const int c = seg * 8 + j;
            ylnl16[qs][c] = f2bf((v[j] - mean) * rs * g_f[c] + be_f[c]);
        }
    }
    __syncthreads();                                  // B3

    // fc1 GEMM + gelu -> h1l16 (bf16)
    {
        f32x4 acc0 = {0.f,0.f,0.f,0.f}, acc1 = {0.f,0.f,0.f,0.f};
        #pragma unroll
        for (int kt = 0; kt < 4; ++kt) {
            const short8 a = *(const short8*)&ylnl16[llo][kt*32 + lhi*8];
            const short8 b0 = *(const short8*)&wfc1_s[(size_t)(((wave    )*4 + kt)*64 + lane)*8];
            const short8 b1 = *(const short8*)&wfc1_s[(size_t)(((wave + 4)*4 + kt)*64 + lane)*8];
            acc0 = __builtin_amdgcn_mfma_f32_16x16x32_bf16(a, b0, acc0, 0, 0, 0);
            acc1 = __builtin_amdgcn_mfma_f32_16x16x32_bf16(a, b1, acc1, 0, 0, 0);
        }
        #pragma unroll
        for (int qe = 0; qe < 4; ++qe) {
            const int row = lhi * 4 + qe;
            const int c0 = wave * 16 + llo, c1 = (wave + 4) * 16 + llo;
            h1l16[row][c0] = f2bf(gelu_exact(acc0[qe] + b_fc1[c0]));
            h1l16[row][c1] = f2bf(gelu_exact(acc1[qe] + b_fc1[c1]));
        }
    }
    __syncthreads();                                  // B4

    // fc2 GEMM + b_fc2 + xf -> sclp (reuse)
    {
        f32x4 acc0 = {0.f,0.f,0.f,0.f}, acc1 = {0.f,0.f,0.f,0.f};
        #pragma unroll
        for (int kt = 0; kt < 4; ++kt) {
            const short8 a = *(const short8*)&h1l16[llo][kt*32 + lhi*8];
            const short8 b0 = *(const short8*)&wfc2_s[(size_t)(((wave    )*4 + kt)*64 + lane)*8];
            const short8 b1 = *(const short8*)&wfc2_s[(size_t)(((wave + 4)*4 + kt)*64 + lane)*8];
            acc0 = __builtin_amdgcn_mfma_f32_16x16x32_bf16(a, b0, acc0, 0, 0, 0);
            acc1 = __builtin_amdgcn_mfma_f32_16x16x32_bf16(a, b1, acc1, 0, 0, 0);
        }
        #pragma unroll
        for (int qe = 0; qe < 4; ++qe) {
            const int row = lhi * 4 + qe;
            const int c0 = wave * 16 + llo, c1 = (wave + 4) * 16 + llo;
            sclp[row][c0] = acc0[qe] + b_fc2[c0] + xfl[row][c0];
            sclp[row][c1] = acc1[qe] + b_fc2[c1] + xfl[row][c1];
        }
    }
    __syncthreads();                                  // B5

    // coalesced write scfeat
    {
        float* dst = scfeat + (size_t)mq * C_IN + seg * 8;
        *(float4*)&dst[0] = make_float4(sclp[qs][seg*8+0], sclp[qs][seg*8+1],
                                        sclp[qs][seg*8+2], sclp[qs][seg*8+3]);
        *(float4*)&dst[4] = make_float4(sclp[qs][seg*8+4], sclp[qs][seg*8+5],
                                        sclp[qs][seg*8+6], sclp[qs][seg*8+7]);
    }
}

extern "C" void kernel_launch(void* const* d_in, const int* in_sizes, int n_in,
                              void* d_out, int out_size, void* d_ws, size_t ws_size,
                              hipStream_t stream) {
    const float* vf    = (const float*)d_in[0];
    const int*   spi   = (const int*)  d_in[1];
    const int*   ni    = (const int*)  d_in[2];
    const int*   kidx  = (const int*)  d_in[3];
    const float* bev   = (const float*)d_in[4];
    const float* w_pos = (const float*)d_in[5];
    const float* b_pos = (const float*)d_in[6];
    const float* w_bev = (const float*)d_in[7];
    const float* b_bev = (const float*)d_in[8];
    const float* g_q   = (const float*)d_in[9];
    const float* be_q  = (const float*)d_in[10];
    const float* g_k   = (const float*)d_in[11];
    const float* be_k  = (const float*)d_in[12];
    const float* g_f   = (const float*)d_in[13];
    const float* be_f  = (const float*)d_in[14];
    const float* w_in  = (const float*)d_in[15];
    const float* b_in  = (const float*)d_in[16];
    const float* w_out = (const float*)d_in[17];
    const float* b_out = (const float*)d_in[18];
    const float* w_fc1 = (const float*)d_in[19];
    const float* b_fc1 = (const float*)d_in[20];
    const float* w_fc2 = (const float*)d_in[21];
    const float* b_fc2 = (const float*)d_in[22];
    float* out = (float*)d_out;

    const int M = in_sizes[3] / NKEY;

    // ---- workspace:
    //  inv    @0      (1.98 MiB)
    //  pack   @2MiB   [M][256] f32: bevq -> [0:128]=qh, [128:256]=av
    //  scfeat @32MiB  [M][128] f32: sc, then featbuf in-place
    //  weights @47MiB: swizzled bf16: wbev(64KB) wq(32KB) wout(32KB) wfc1(32KB) wfc2(32KB)
    char* ws = (char*)d_ws;
    const size_t MiB = 1u << 20;
    int*    inv    = (int*)ws;
    float*  pack   = (float*)(ws + 2 * MiB);
    float*  scfeat = (float*)(ws + 32 * MiB);
    ushort* wbev_s = (ushort*)(ws + 47 * MiB);
    ushort* wq_s   = wbev_s + 128 * 256;
    ushort* wout_s = wq_s   + 128 * 128;
    ushort* wfc1_s = wout_s + 128 * 128;
    ushort* wfc2_s = wfc1_s + 128 * 128;

    hipMemsetAsync(inv, 0xFF, (size_t)4 * H_Y * W_X * sizeof(int), stream);
    build_inv<<<(M + 255) / 256, 256, 0, stream>>>(ni, inv, M);

    conv_swz<<<128, 256, 0, stream>>>(w_bev, wbev_s, C_BEV, 128 * 256);
    conv_swz<<<64, 256, 0, stream>>>(w_in,  wq_s,   C_IN, 128 * 128);
    conv_swz<<<64, 256, 0, stream>>>(w_out, wout_s, C_IN, 128 * 128);
    conv_swz<<<64, 256, 0, stream>>>(w_fc1, wfc1_s, C_IN, 128 * 128);
    conv_swz<<<64, 256, 0, stream>>>(w_fc2, wfc2_s, C_IN, 128 * 128);

    compact_bev<<<4 * H_Y * 12, 256, 0, stream>>>(bev, inv, pack);

    k_pre<<<(M + 15) / 16, 256, 0, stream>>>(pack, wbev_s, b_bev, g_q, be_q,
                                             wq_s, b_in, scfeat, M);
    k_attn<<<(M + 1) / 2, 512, 0, stream>>>(vf, spi, ni, kidx, pack, w_pos, b_pos,
                                            g_k, be_k, w_in, b_in, M);
    k_post<<<(M + 15) / 16, 256, 0, stream>>>(pack, wout_s, b_out, g_f, be_f,
                                              wfc1_s, b_fc1, wfc2_s, b_fc2, scfeat, M);

    write_out_t<<<4 * H_Y * 12, 256, 0, stream>>>(inv, scfeat, out);
}

// Round 22
// 663.530 us; speedup vs baseline: 2.6002x; 1.0920x over previous
//
#include <hip/hip_runtime.h>
#include <hip/hip_bf16.h>
#include <cmath>

#define C_IN 128
#define NKEY 32
#define N_H 4
#define D_H 32
#define C_BEV 256
#define H_Y 180
#define W_X 180

typedef __attribute__((ext_vector_type(8))) short short8;
typedef __attribute__((ext_vector_type(4))) float f32x4;

__device__ __forceinline__ float gelu_exact(float x) {
    return 0.5f * x * (1.0f + erff(x * 0.7071067811865475f));
}
__device__ __forceinline__ float dot4(float4 a, float4 b) {
    return a.x * b.x + a.y * b.y + a.z * b.z + a.w * b.w;
}
__device__ __forceinline__ float bf2f(ushort u) {
    union { unsigned int i; float f; } c; c.i = ((unsigned int)u) << 16; return c.f;
}
__device__ __forceinline__ ushort f2bf(float x) {
    __hip_bfloat16 h = __float2bfloat16(x);
    return *reinterpret_cast<ushort*>(&h);
}

// ---- one-time: f32 weight [OUT][K] -> bf16 MFMA fragment order (verified R21)
__global__ void conv_swz(const float* __restrict__ src, ushort* __restrict__ dst,
                         int K, int total) {
    const int idx = blockIdx.x * 256 + threadIdx.x;
    if (idx < total) {
        const int j = idx & 7;
        const int t8 = idx >> 3;
        const int lane = t8 & 63;
        const int tile = t8 >> 6;
        const int NK = K >> 5;
        const int kt = tile % NK, ct = tile / NK;
        const int row = ct * 16 + (lane & 15);
        const int k = kt * 32 + (lane >> 4) * 8 + j;
        dst[idx] = f2bf(src[(size_t)row * K + k]);
    }
}

// ---- inv[cell] = m  (inv pre-memset to -1)
__global__ void build_inv(const int* __restrict__ ni, int* __restrict__ inv, int M) {
    const int m = blockIdx.x * 256 + threadIdx.x;
    if (m < M) {
        const int b = ni[m*4+0], y = ni[m*4+2], x = ni[m*4+3];
        inv[(b * H_Y + y) * W_X + x] = m;
    }
}

// ---- compact bev -> pack[m][0:256] contiguous (verified R8/R13)
__global__ __launch_bounds__(256) void compact_bev(
    const float* __restrict__ bev, const int* __restrict__ inv,
    float* __restrict__ pack)
{
    const int bid = blockIdx.x;
    const int xr = bid % 12;
    const int y  = (bid / 12) % H_Y;
    const int b  = bid / (12 * H_Y);
    const int x0 = xr * 16;
    const int width = (x0 + 16 <= W_X) ? 16 : (W_X - x0);
    const int tid = threadIdx.x;

    __shared__ float tile[16][257];

    const int xq = (tid & 3) * 4;
    #pragma unroll
    for (int p = 0; p < 4; ++p) {
        const int c = p * 64 + (tid >> 2);
        if (xq < width) {
            const float4 v = *(const float4*)(bev +
                (((size_t)b * C_BEV + c) * H_Y + y) * W_X + x0 + xq);
            tile[xq+0][c] = v.x; tile[xq+1][c] = v.y;
            tile[xq+2][c] = v.z; tile[xq+3][c] = v.w;
        }
    }
    __syncthreads();
    for (int xi = 0; xi < width; ++xi) {
        const int m = inv[(b * H_Y + y) * W_X + x0 + xi];
        if (m >= 0) pack[(size_t)m * C_BEV + tid] = tile[xi][tid];
    }
}

// ---- transposed write-out (verified R19)
__global__ __launch_bounds__(256) void write_out_t(
    const int* __restrict__ inv, const float* __restrict__ featbuf,
    float* __restrict__ out)
{
    const int bid = blockIdx.x;
    const int xr = bid % 12;
    const int y  = (bid / 12) % H_Y;
    const int b  = bid / (12 * H_Y);
    const int x0 = xr * 16;
    const int width = (x0 + 16 <= W_X) ? 16 : (W_X - x0);
    const int tid = threadIdx.x;

    __shared__ float tile[16][C_IN + 1];
    __shared__ int m16[16];

    if (tid < 16) m16[tid] = (tid < width) ? inv[(b * H_Y + y) * W_X + x0 + tid] : -1;
    __syncthreads();

    #pragma unroll
    for (int pass = 0; pass < 8; ++pass) {
        const int xi = pass * 2 + (tid >> 7);
        const int c  = tid & 127;
        const int m  = m16[xi];
        tile[xi][c] = (m >= 0) ? featbuf[(size_t)m * C_IN + c] : 0.0f;
    }
    __syncthreads();

    #pragma unroll
    for (int pass = 0; pass < 8; ++pass) {
        const int c  = pass * 16 + (tid >> 4);
        const int xi = tid & 15;
        if (xi < width)
            out[(((size_t)b * C_IN + c) * H_Y + y) * W_X + x0 + xi] = tile[xi][c];
    }
}

// ---- MFMA pre-attention (verified R21): 16 queries / 256-thread block.
__global__ __launch_bounds__(256) void k_pre(
    float* __restrict__ pack, const ushort* __restrict__ wbev_s,
    const float* __restrict__ b_bev, const float* __restrict__ g_q,
    const float* __restrict__ be_q, const ushort* __restrict__ wq_s,
    const float* __restrict__ b_in, float* __restrict__ sc_g, const int M)
{
    __shared__ ushort bevl16[16][C_BEV + 8];
    __shared__ float  scl[16][C_IN];
    __shared__ ushort qlnl16[16][C_IN + 8];
    const int tid = threadIdx.x;
    const int m16 = blockIdx.x * 16;
    const int wave = tid >> 6, lane = tid & 63;
    const int llo = lane & 15, lhi = lane >> 4;
    const int qs = tid >> 4, seg = tid & 15;
    int mq = m16 + qs; if (mq >= M) mq = M - 1;

    {
        const float4* srcp = (const float4*)(pack + (size_t)mq * C_BEV + seg * 16);
        ushort tmp[16];
        #pragma unroll
        for (int j4 = 0; j4 < 4; ++j4) {
            const float4 v = srcp[j4];
            tmp[j4*4+0] = f2bf(v.x); tmp[j4*4+1] = f2bf(v.y);
            tmp[j4*4+2] = f2bf(v.z); tmp[j4*4+3] = f2bf(v.w);
        }
        short8* d = (short8*)&bevl16[qs][seg * 16];
        d[0] = *(short8*)&tmp[0];
        d[1] = *(short8*)&tmp[8];
    }
    __syncthreads();

    {
        f32x4 acc0 = {0.f,0.f,0.f,0.f}, acc1 = {0.f,0.f,0.f,0.f};
        #pragma unroll
        for (int kt = 0; kt < 8; ++kt) {
            const short8 a = *(const short8*)&bevl16[llo][kt*32 + lhi*8];
            const short8 b0 = *(const short8*)&wbev_s[(size_t)(((wave    )*8 + kt)*64 + lane)*8];
            const short8 b1 = *(const short8*)&wbev_s[(size_t)(((wave + 4)*8 + kt)*64 + lane)*8];
            acc0 = __builtin_amdgcn_mfma_f32_16x16x32_bf16(a, b0, acc0, 0, 0, 0);
            acc1 = __builtin_amdgcn_mfma_f32_16x16x32_bf16(a, b1, acc1, 0, 0, 0);
        }
        #pragma unroll
        for (int qe = 0; qe < 4; ++qe) {
            const int row = lhi * 4 + qe;
            const int c0 = wave * 16 + llo, c1 = (wave + 4) * 16 + llo;
            scl[row][c0] = gelu_exact(acc0[qe] + b_bev[c0]);
            scl[row][c1] = gelu_exact(acc1[qe] + b_bev[c1]);
        }
    }
    __syncthreads();

    {
        float* dst = sc_g + (size_t)mq * C_IN + seg * 8;
        float v[8];
        #pragma unroll
        for (int j = 0; j < 8; ++j) v[j] = scl[qs][seg * 8 + j];
        *(float4*)&dst[0] = make_float4(v[0], v[1], v[2], v[3]);
        *(float4*)&dst[4] = make_float4(v[4], v[5], v[6], v[7]);

        float s = 0.f;
        #pragma unroll
        for (int j = 0; j < 8; ++j) s += v[j];
        s += __shfl_xor(s, 1); s += __shfl_xor(s, 2);
        s += __shfl_xor(s, 4); s += __shfl_xor(s, 8);
        const float mean = s * (1.0f / 128.0f);
        float vv = 0.f;
        #pragma unroll
        for (int j = 0; j < 8; ++j) { const float d = v[j] - mean; vv += d * d; }
        vv += __shfl_xor(vv, 1); vv += __shfl_xor(vv, 2);
        vv += __shfl_xor(vv, 4); vv += __shfl_xor(vv, 8);
        const float rs = rsqrtf(vv * (1.0f / 128.0f) + 1e-5f);
        #pragma unroll
        for (int j = 0; j < 8; ++j) {
            const int c = seg * 8 + j;
            qlnl16[qs][c] = f2bf((v[j] - mean) * rs * g_q[c] + be_q[c]);
        }
    }
    __syncthreads();

    {
        f32x4 acc0 = {0.f,0.f,0.f,0.f}, acc1 = {0.f,0.f,0.f,0.f};
        #pragma unroll
        for (int kt = 0; kt < 4; ++kt) {
            const short8 a = *(const short8*)&qlnl16[llo][kt*32 + lhi*8];
            const short8 b0 = *(const short8*)&wq_s[(size_t)(((wave    )*4 + kt)*64 + lane)*8];
            const short8 b1 = *(const short8*)&wq_s[(size_t)(((wave + 4)*4 + kt)*64 + lane)*8];
            acc0 = __builtin_amdgcn_mfma_f32_16x16x32_bf16(a, b0, acc0, 0, 0, 0);
            acc1 = __builtin_amdgcn_mfma_f32_16x16x32_bf16(a, b1, acc1, 0, 0, 0);
        }
        #pragma unroll
        for (int qe = 0; qe < 4; ++qe) {
            const int row = lhi * 4 + qe;
            const int c0 = wave * 16 + llo, c1 = (wave + 4) * 16 + llo;
            scl[row][c0] = acc0[qe] + b_in[c0];
            scl[row][c1] = acc1[qe] + b_in[c1];
        }
    }
    __syncthreads();

    {
        float* dst = pack + (size_t)mq * C_BEV + seg * 8;
        *(float4*)&dst[0] = make_float4(scl[qs][seg*8+0], scl[qs][seg*8+1],
                                        scl[qs][seg*8+2], scl[qs][seg*8+3]);
        *(float4*)&dst[4] = make_float4(scl[qs][seg*8+4], scl[qs][seg*8+5],
                                        scl[qs][seg*8+6], scl[qs][seg*8+7]);
    }
}

// ---- attention kernel: 2q/512t. NEW: mask-compacted gather + LDS param staging.
__global__ __launch_bounds__(512) void k_attn(
    const float* __restrict__ vf, const int* __restrict__ spi,
    const int* __restrict__ ni, const int* __restrict__ kidx,
    float* __restrict__ pack,
    const float* __restrict__ w_pos, const float* __restrict__ b_pos,
    const float* __restrict__ g_k, const float* __restrict__ be_k,
    const float* __restrict__ w_in, const float* __restrict__ b_in,
    const int M)
{
    const int tid = threadIdx.x;
    const int m2 = blockIdx.x * 2;
    const int mA = m2;
    const int mB = (m2 + 1 < M) ? (m2 + 1) : (M - 1);

    __shared__ ushort kf16[64][C_IN + 8];
    __shared__ float qhs[2 * C_IN];
    __shared__ float tk[2 * 4 * C_IN];
    __shared__ float attnw[2 * 4 * NKEY];
    __shared__ int   kmsk[64];
    __shared__ int   kvs[64];
    __shared__ int   lst[64];
    __shared__ int   cntS;
    __shared__ float prm[768];   // w_pos[384] | b_pos[128] | g_k[128] | be_k[128]

    const int nxA = ni[mA*4+3], nyA = ni[mA*4+2];
    const int nxB = ni[mB*4+3], nyB = ni[mB*4+2];

    // stage params (coalesced) + qh + masks/compact-list, all pre-barrier
    for (int i = tid; i < 768; i += 512) {
        float val;
        if (i < 384)      val = w_pos[i];
        else if (i < 512) val = b_pos[i - 384];
        else if (i < 640) val = g_k[i - 512];
        else              val = be_k[i - 640];
        prm[i] = val;
    }
    if (tid < 256) {
        const int q = tid >> 7, idx = tid & 127;
        qhs[q * 128 + idx] = pack[(size_t)(q ? mB : mA) * C_BEV + idx];
    }
    if (tid < 64) {
        const int qk = tid >> 5;
        const int kv = kidx[(size_t)(qk ? mB : mA) * NKEY + (tid & 31)];
        const bool act = (kv >= 0);
        kmsk[tid] = act ? 0 : 1;
        kvs[tid]  = act ? kv : 0;
        const unsigned long long bal = __ballot(act);
        if (tid == 0) cntS = (int)__popcll(bal);
        if (act) lst[(int)__popcll(bal & ((1ull << tid) - 1ull))] = tid;
    }
    __syncthreads();                                  // B1

    // P1: zero masked rows; gather+posemb+LN only for active rows (compacted)
    {
        const int grp = tid >> 3, g = tid & 7, c0 = g * 16;
        if (kmsk[grp]) {
            const short8 z = (short8){0,0,0,0,0,0,0,0};
            short8* d = (short8*)&kf16[grp][c0];
            d[0] = z; d[1] = z;
        }
        if (grp < cntS) {
            const int kk = lst[grp];
            const int qk = kk >> 5;
            const int safe = kvs[kk];
            const int nxk = qk ? nxB : nxA, nyk = qk ? nyB : nyA;
            const float qxk = (nxk + 0.5f) * (150.4f / 180.0f) - 75.2f;
            const float qyk = (nyk + 0.5f) * (150.4f / 180.0f) - 75.2f;
            const int sz = spi[safe * 4 + 1];
            const int sy = spi[safe * 4 + 2];
            const int sx = spi[safe * 4 + 3];
            const float cx = (sx + 0.5f) * (150.4f / 1440.0f) - 75.2f - qxk;
            const float cy = (sy + 0.5f) * (150.4f / 1440.0f) - 75.2f - qyk;
            const float cz = (sz + 0.5f) * (6.0f / 40.0f)     - 3.0f;

            float v[16];
            const float4* src = (const float4*)(vf + (size_t)safe * C_IN + c0);
            #pragma unroll
            for (int j = 0; j < 4; ++j) {
                float4 t = src[j];
                v[j*4+0] = t.x; v[j*4+1] = t.y; v[j*4+2] = t.z; v[j*4+3] = t.w;
            }
            // posemb + gelu, 2 chunks of 8 channels (params via LDS float4)
            #pragma unroll
            for (int ch = 0; ch < 2; ++ch) {
                const int cb = c0 + ch * 8;
                float wpl[24];
                const float4* wpr = (const float4*)&prm[cb * 3];
                #pragma unroll
                for (int j4 = 0; j4 < 6; ++j4) *(float4*)&wpl[j4*4] = wpr[j4];
                float bpl[8];
                *(float4*)&bpl[0] = *(const float4*)&prm[384 + cb];
                *(float4*)&bpl[4] = *(const float4*)&prm[384 + cb + 4];
                #pragma unroll
                for (int j = 0; j < 8; ++j) {
                    const float e = cx*wpl[j*3+0] + cy*wpl[j*3+1] + cz*wpl[j*3+2] + bpl[j];
                    v[ch*8+j] += gelu_exact(e);
                }
            }
            // LN over 128 ch (8-lane group reduce; groups fully active or inactive)
            float s = 0.f;
            #pragma unroll
            for (int j = 0; j < 16; ++j) s += v[j];
            s += __shfl_xor(s, 1); s += __shfl_xor(s, 2); s += __shfl_xor(s, 4);
            const float mean = s * (1.0f / 128.0f);
            float vv = 0.f;
            #pragma unroll
            for (int j = 0; j < 16; ++j) { const float d = v[j] - mean; vv += d * d; }
            vv += __shfl_xor(vv, 1); vv += __shfl_xor(vv, 2); vv += __shfl_xor(vv, 4);
            const float rs = rsqrtf(vv * (1.0f / 128.0f) + 1e-5f);
            ushort o[16];
            #pragma unroll
            for (int ch = 0; ch < 2; ++ch) {
                const int cb = c0 + ch * 8;
                float gkl[8], bel[8];
                *(float4*)&gkl[0] = *(const float4*)&prm[512 + cb];
                *(float4*)&gkl[4] = *(const float4*)&prm[512 + cb + 4];
                *(float4*)&bel[0] = *(const float4*)&prm[640 + cb];
                *(float4*)&bel[4] = *(const float4*)&prm[640 + cb + 4];
                #pragma unroll
                for (int j = 0; j < 8; ++j)
                    o[ch*8+j] = f2bf((v[ch*8+j] - mean) * rs * gkl[j] + bel[j]);
            }
            short8* drow = (short8*)(&kf16[kk][c0]);
            drow[0] = *(short8*)&o[0];
            drow[1] = *(short8*)&o[8];
        }
    }
    __syncthreads();                                  // B2

    // t[h] = qh_h @ wk_h (unchanged)
    {
        const int q = tid >> 8, r = tid & 255;
        const int c = r & 127, h2 = r >> 7;
        #pragma unroll
        for (int hi = 0; hi < 2; ++hi) {
            const int hh = h2 + 2 * hi;
            float acc = 0.f;
            #pragma unroll
            for (int d = 0; d < D_H; ++d)
                acc += qhs[q*128 + hh*D_H + d] * w_in[(size_t)(C_IN + hh*D_H + d) * C_IN + c];
            tk[(q*4 + hh)*128 + c] = acc;
        }
    }
    __syncthreads();                                  // B3

    // logits + masked softmax (unchanged)
    {
        const int q = tid >> 8, r = tid & 255;
        const int h = r >> 6, half = (r >> 5) & 1, p = r & 31;
        float tbv = qhs[q*128 + h*D_H + p] * b_in[C_IN + h*D_H + p];
        #pragma unroll
        for (int o = 16; o >= 1; o >>= 1) tbv += __shfl_xor(tbv, o);
        const float* tr = &tk[(q*4 + h)*128 + half*64];
        const ushort* kr = &kf16[q*NKEY + p][half*64];
        float d = 0.f;
        #pragma unroll
        for (int c2 = 0; c2 < 32; ++c2) {
            const uint u = *(const uint*)&kr[c2*2];
            d += tr[c2*2]   * bf2f((ushort)(u & 0xffff));
            d += tr[c2*2+1] * bf2f((ushort)(u >> 16));
        }
        d += __shfl_xor(d, 32);
        const int msk = kmsk[q*NKEY + p];
        float logit = msk ? -3.0e38f : (d + tbv) * 0.17677669529663687f;
        float mx = logit;
        #pragma unroll
        for (int o = 16; o >= 1; o >>= 1) mx = fmaxf(mx, __shfl_xor(mx, o));
        const float e = msk ? 0.0f : expf(logit - mx);
        float ssum = e;
        #pragma unroll
        for (int o = 16; o >= 1; o >>= 1) ssum += __shfl_xor(ssum, o);
        if (half == 0) attnw[(q*4 + h)*32 + p] = e / ssum;
    }
    __syncthreads();                                  // B4

    // kbar (unchanged; masked rows are zeros)
    {
        const int q = tid >> 8, r = tid & 255;
        const int c = r & 127, h2 = r >> 7;
        #pragma unroll
        for (int hi = 0; hi < 2; ++hi) {
            const int hh = h2 + 2 * hi;
            float acc = 0.f;
            #pragma unroll
            for (int p = 0; p < NKEY; ++p)
                acc += attnw[(q*4 + hh)*32 + p] * bf2f(kf16[q*NKEY + p][c]);
            tk[(q*4 + hh)*128 + c] = acc;
        }
    }
    __syncthreads();                                  // B5

    // av (unchanged)
    {
        const int wave = tid >> 6, lane = tid & 63;
        #pragma unroll 4
        for (int t = wave; t < 128; t += 8) {
            const int row = t * 2 + (lane >> 5);
            const int q = row >> 7, j = row & 127;
            const int h = j >> 5;
            const float4 w4 = ((const float4*)(w_in + (size_t)(2*C_IN + j) * C_IN))[lane & 31];
            const float4 k4 = ((const float4*)&tk[(q*4 + h)*128])[lane & 31];
            float a = dot4(w4, k4);
            a += __shfl_xor(a, 1); a += __shfl_xor(a, 2); a += __shfl_xor(a, 4);
            a += __shfl_xor(a, 8); a += __shfl_xor(a, 16);
            if ((lane & 31) == 0 && (m2 + q) < M)
                pack[(size_t)(q ? mB : mA) * C_BEV + C_IN + j] = a + b_in[2*C_IN + j];
        }
    }
}

// ---- MFMA post-attention (verified R21): 16 queries / 256-thread block.
__global__ __launch_bounds__(256) void k_post(
    const float* __restrict__ pack,
    const ushort* __restrict__ wout_s, const float* __restrict__ b_out,
    const float* __restrict__ g_f, const float* __restrict__ be_f,
    const ushort* __restrict__ wfc1_s, const float* __restrict__ b_fc1,
    const ushort* __restrict__ wfc2_s, const float* __restrict__ b_fc2,
    float* __restrict__ scfeat, const int M)
{
    __shared__ ushort avl16[16][C_IN + 8];
    __shared__ float  sclp[16][C_IN];
    __shared__ float  xfl[16][C_IN];
    __shared__ ushort ylnl16[16][C_IN + 8];
    __shared__ ushort h1l16[16][C_IN + 8];
    const int tid = threadIdx.x;
    const int m16 = blockIdx.x * 16;
    const int wave = tid >> 6, lane = tid & 63;
    const int llo = lane & 15, lhi = lane >> 4;
    const int qs = tid >> 4, seg = tid & 15;
    int mq = m16 + qs; if (mq >= M) mq = M - 1;

    {
        const float4* ap = (const float4*)(pack + (size_t)mq * C_BEV + C_IN + seg * 8);
        const float4 a0 = ap[0], a1 = ap[1];
        ushort tmp[8];
        tmp[0]=f2bf(a0.x); tmp[1]=f2bf(a0.y); tmp[2]=f2bf(a0.z); tmp[3]=f2bf(a0.w);
        tmp[4]=f2bf(a1.x); tmp[5]=f2bf(a1.y); tmp[6]=f2bf(a1.z); tmp[7]=f2bf(a1.w);
        *(short8*)&avl16[qs][seg * 8] = *(short8*)&tmp[0];
        const float4* sp = (const float4*)(scfeat + (size_t)mq * C_IN + seg * 8);
        *(float4*)&sclp[qs][seg * 8]     = sp[0];
        *(float4*)&sclp[qs][seg * 8 + 4] = sp[1];
    }
    __syncthreads();

    {
        f32x4 acc0 = {0.f,0.f,0.f,0.f}, acc1 = {0.f,0.f,0.f,0.f};
        #pragma unroll
        for (int kt = 0; kt < 4; ++kt) {
            const short8 a = *(const short8*)&avl16[llo][kt*32 + lhi*8];
            const short8 b0 = *(const short8*)&wout_s[(size_t)(((wave    )*4 + kt)*64 + lane)*8];
            const short8 b1 = *(const short8*)&wout_s[(size_t)(((wave + 4)*4 + kt)*64 + lane)*8];
            acc0 = __builtin_amdgcn_mfma_f32_16x16x32_bf16(a, b0, acc0, 0, 0, 0);
            acc1 = __builtin_amdgcn_mfma_f32_16x16x32_bf16(a, b1, acc1, 0, 0, 0);
        }
        #pragma unroll
        for (int qe = 0; qe < 4; ++qe) {
            const int row = lhi * 4 + qe;
            const int c0 = wave * 16 + llo, c1 = (wave + 4) * 16 + llo;
            xfl[row][c0] = acc0[qe] + b_out[c0] + sclp[row][c0];
            xfl[row][c1] = acc1[qe] + b_out[c1] + sclp[row][c1];
        }
    }
    __syncthreads();

    {
        float v[8];
        #pragma unroll
        for (int j = 0; j < 8; ++j) v[j] = xfl[qs][seg * 8 + j];
        float s = 0.f;
        #pragma unroll
        for (int j = 0; j < 8; ++j) s += v[j];
        s += __shfl_xor(s, 1); s += __shfl_xor(s, 2);
        s += __shfl_xor(s, 4); s += __shfl_xor(s, 8);
        const float mean = s * (1.0f / 128.0f);
        float vv = 0.f;
        #pragma unroll
        for (int j = 0; j < 8; ++j) { const float d = v[j] - mean; vv += d * d; }
        vv += __shfl_xor(vv, 1); vv += __shfl_xor(vv, 2);
        vv += __shfl_xor(vv, 4); vv += __shfl_xor(vv, 8);
        const float rs = rsqrtf(vv * (1.0f / 128.0f) + 1e-5f);
        #pragma unroll
        for (int j = 0; j < 8; ++j) {
            const int c = seg * 8 + j;
            ylnl16[qs][c] = f2bf((v[j] - mean) * rs * g_f[c] + be_f[c]);
        }
    }
    __syncthreads();

    {
        f32x4 acc0 = {0.f,0.f,0.f,0.f}, acc1 = {0.f,0.f,0.f,0.f};
        #pragma unroll
        for (int kt = 0; kt < 4; ++kt) {
            const short8 a = *(const short8*)&ylnl16[llo][kt*32 + lhi*8];
            const short8 b0 = *(const short8*)&wfc1_s[(size_t)(((wave    )*4 + kt)*64 + lane)*8];
            const short8 b1 = *(const short8*)&wfc1_s[(size_t)(((wave + 4)*4 + kt)*64 + lane)*8];
            acc0 = __builtin_amdgcn_mfma_f32_16x16x32_bf16(a, b0, acc0, 0, 0, 0);
            acc1 = __builtin_amdgcn_mfma_f32_16x16x32_bf16(a, b1, acc1, 0, 0, 0);
        }
        #pragma unroll
        for (int qe = 0; qe < 4; ++qe) {
            const int row = lhi * 4 + qe;
            const int c0 = wave * 16 + llo, c1 = (wave + 4) * 16 + llo;
            h1l16[row][c0] = f2bf(gelu_exact(acc0[qe] + b_fc1[c0]));
            h1l16[row][c1] = f2bf(gelu_exact(acc1[qe] + b_fc1[c1]));
        }
    }
    __syncthreads();

    {
        f32x4 acc0 = {0.f,0.f,0.f,0.f}, acc1 = {0.f,0.f,0.f,0.f};
        #pragma unroll
        for (int kt = 0; kt < 4; ++kt) {
            const short8 a = *(const short8*)&h1l16[llo][kt*32 + lhi*8];
            const short8 b0 = *(const short8*)&wfc2_s[(size_t)(((wave    )*4 + kt)*64 + lane)*8];
            const short8 b1 = *(const short8*)&wfc2_s[(size_t)(((wave + 4)*4 + kt)*64 + lane)*8];
            acc0 = __builtin_amdgcn_mfma_f32_16x16x32_bf16(a, b0, acc0, 0, 0, 0);
            acc1 = __builtin_amdgcn_mfma_f32_16x16x32_bf16(a, b1, acc1, 0, 0, 0);
        }
        #pragma unroll
        for (int qe = 0; qe < 4; ++qe) {
            const int row = lhi * 4 + qe;
            const int c0 = wave * 16 + llo, c1 = (wave + 4) * 16 + llo;
            sclp[row][c0] = acc0[qe] + b_fc2[c0] + xfl[row][c0];
            sclp[row][c1] = acc1[qe] + b_fc2[c1] + xfl[row][c1];
        }
    }
    __syncthreads();

    {
        float* dst = scfeat + (size_t)mq * C_IN + seg * 8;
        *(float4*)&dst[0] = make_float4(sclp[qs][seg*8+0], sclp[qs][seg*8+1],
                                        sclp[qs][seg*8+2], sclp[qs][seg*8+3]);
        *(float4*)&dst[4] = make_float4(sclp[qs][seg*8+4], sclp[qs][seg*8+5],
                                        sclp[qs][seg*8+6], sclp[qs][seg*8+7]);
    }
}

extern "C" void kernel_launch(void* const* d_in, const int* in_sizes, int n_in,
                              void* d_out, int out_size, void* d_ws, size_t ws_size,
                              hipStream_t stream) {
    const float* vf    = (const float*)d_in[0];
    const int*   spi   = (const int*)  d_in[1];
    const int*   ni    = (const int*)  d_in[2];
    const int*   kidx  = (const int*)  d_in[3];
    const float* bev   = (const float*)d_in[4];
    const float* w_pos = (const float*)d_in[5];
    const float* b_pos = (const float*)d_in[6];
    const float* w_bev = (const float*)d_in[7];
    const float* b_bev = (const float*)d_in[8];
    const float* g_q   = (const float*)d_in[9];
    const float* be_q  = (const float*)d_in[10];
    const float* g_k   = (const float*)d_in[11];
    const float* be_k  = (const float*)d_in[12];
    const float* g_f   = (const float*)d_in[13];
    const float* be_f  = (const float*)d_in[14];
    const float* w_in  = (const float*)d_in[15];
    const float* b_in  = (const float*)d_in[16];
    const float* w_out = (const float*)d_in[17];
    const float* b_out = (const float*)d_in[18];
    const float* w_fc1 = (const float*)d_in[19];
    const float* b_fc1 = (const float*)d_in[20];
    const float* w_fc2 = (const float*)d_in[21];
    const float* b_fc2 = (const float*)d_in[22];
    float* out = (float*)d_out;

    const int M = in_sizes[3] / NKEY;

    char* ws = (char*)d_ws;
    const size_t MiB = 1u << 20;
    int*    inv    = (int*)ws;
    float*  pack   = (float*)(ws + 2 * MiB);
    float*  scfeat = (float*)(ws + 32 * MiB);
    ushort* wbev_s = (ushort*)(ws + 47 * MiB);
    ushort* wq_s   = wbev_s + 128 * 256;
    ushort* wout_s = wq_s   + 128 * 128;
    ushort* wfc1_s = wout_s + 128 * 128;
    ushort* wfc2_s = wfc1_s + 128 * 128;

    hipMemsetAsync(inv, 0xFF, (size_t)4 * H_Y * W_X * sizeof(int), stream);
    build_inv<<<(M + 255) / 256, 256, 0, stream>>>(ni, inv, M);

    conv_swz<<<128, 256, 0, stream>>>(w_bev, wbev_s, C_BEV, 128 * 256);
    conv_swz<<<64, 256, 0, stream>>>(w_in,  wq_s,   C_IN, 128 * 128);
    conv_swz<<<64, 256, 0, stream>>>(w_out, wout_s, C_IN, 128 * 128);
    conv_swz<<<64, 256, 0, stream>>>(w_fc1, wfc1_s, C_IN, 128 * 128);
    conv_swz<<<64, 256, 0, stream>>>(w_fc2, wfc2_s, C_IN, 128 * 128);

    compact_bev<<<4 * H_Y * 12, 256, 0, stream>>>(bev, inv, pack);

    k_pre<<<(M + 15) / 16, 256, 0, stream>>>(pack, wbev_s, b_bev, g_q, be_q,
                                             wq_s, b_in, scfeat, M);
    k_attn<<<(M + 1) / 2, 512, 0, stream>>>(vf, spi, ni, kidx, pack, w_pos, b_pos,
                                            g_k, be_k, w_in, b_in, M);
    k_post<<<(M + 15) / 16, 256, 0, stream>>>(pack, wout_s, b_out, g_f, be_f,
                                              wfc1_s, b_fc1, wfc2_s, b_fc2, scfeat, M);

    write_out_t<<<4 * H_Y * 12, 256, 0, stream>>>(inv, scfeat, out);
}

// Round 23
// 631.794 us; speedup vs baseline: 2.7308x; 1.0502x over previous
//
#include <hip/hip_runtime.h>
#include <hip/hip_bf16.h>
#include <cmath>

#define C_IN 128
#define NKEY 32
#define N_H 4
#define D_H 32
#define C_BEV 256
#define H_Y 180
#define W_X 180

typedef __attribute__((ext_vector_type(8))) short short8;
typedef __attribute__((ext_vector_type(4))) float f32x4;

__device__ __forceinline__ float gelu_exact(float x) {
    return 0.5f * x * (1.0f + erff(x * 0.7071067811865475f));
}
__device__ __forceinline__ float dot4(float4 a, float4 b) {
    return a.x * b.x + a.y * b.y + a.z * b.z + a.w * b.w;
}
__device__ __forceinline__ float bf2f(ushort u) {
    union { unsigned int i; float f; } c; c.i = ((unsigned int)u) << 16; return c.f;
}
__device__ __forceinline__ ushort f2bf(float x) {
    __hip_bfloat16 h = __float2bfloat16(x);
    return *reinterpret_cast<ushort*>(&h);
}

// ---- one-time: f32 weight [OUT][K] -> bf16 MFMA fragment order (verified R21)
__global__ void conv_swz(const float* __restrict__ src, ushort* __restrict__ dst,
                         int K, int total) {
    const int idx = blockIdx.x * 256 + threadIdx.x;
    if (idx < total) {
        const int j = idx & 7;
        const int t8 = idx >> 3;
        const int lane = t8 & 63;
        const int tile = t8 >> 6;
        const int NK = K >> 5;
        const int kt = tile % NK, ct = tile / NK;
        const int row = ct * 16 + (lane & 15);
        const int k = kt * 32 + (lane >> 4) * 8 + j;
        dst[idx] = f2bf(src[(size_t)row * K + k]);
    }
}

// ---- one-time: wk^T per head -> fragment order for t-GEMM.
//  tile (h, ct): value[lane][j] = w_in[(128 + h*32 + (lane>>4)*8 + j)*128 + ct*16 + (lane&15)]
__global__ void conv_swz_t(const float* __restrict__ w_in, ushort* __restrict__ dst) {
    const int idx = blockIdx.x * 256 + threadIdx.x;   // 4*8*64*8 = 16384
    if (idx < 16384) {
        const int j = idx & 7;
        const int lane = (idx >> 3) & 63;
        const int tile = idx >> 9;
        const int ct = tile & 7, h = tile >> 3;
        const int row_w = 128 + h * 32 + (lane >> 4) * 8 + j;
        const int col = ct * 16 + (lane & 15);
        dst[idx] = f2bf(w_in[(size_t)row_w * C_IN + col]);
    }
}

// ---- inv[cell] = m  (inv pre-memset to -1)
__global__ void build_inv(const int* __restrict__ ni, int* __restrict__ inv, int M) {
    const int m = blockIdx.x * 256 + threadIdx.x;
    if (m < M) {
        const int b = ni[m*4+0], y = ni[m*4+2], x = ni[m*4+3];
        inv[(b * H_Y + y) * W_X + x] = m;
    }
}

// ---- compact bev -> pack[m][0:256] contiguous (verified R8/R13)
__global__ __launch_bounds__(256) void compact_bev(
    const float* __restrict__ bev, const int* __restrict__ inv,
    float* __restrict__ pack)
{
    const int bid = blockIdx.x;
    const int xr = bid % 12;
    const int y  = (bid / 12) % H_Y;
    const int b  = bid / (12 * H_Y);
    const int x0 = xr * 16;
    const int width = (x0 + 16 <= W_X) ? 16 : (W_X - x0);
    const int tid = threadIdx.x;

    __shared__ float tile[16][257];

    const int xq = (tid & 3) * 4;
    #pragma unroll
    for (int p = 0; p < 4; ++p) {
        const int c = p * 64 + (tid >> 2);
        if (xq < width) {
            const float4 v = *(const float4*)(bev +
                (((size_t)b * C_BEV + c) * H_Y + y) * W_X + x0 + xq);
            tile[xq+0][c] = v.x; tile[xq+1][c] = v.y;
            tile[xq+2][c] = v.z; tile[xq+3][c] = v.w;
        }
    }
    __syncthreads();
    for (int xi = 0; xi < width; ++xi) {
        const int m = inv[(b * H_Y + y) * W_X + x0 + xi];
        if (m >= 0) pack[(size_t)m * C_BEV + tid] = tile[xi][tid];
    }
}

// ---- transposed write-out (verified R19)
__global__ __launch_bounds__(256) void write_out_t(
    const int* __restrict__ inv, const float* __restrict__ featbuf,
    float* __restrict__ out)
{
    const int bid = blockIdx.x;
    const int xr = bid % 12;
    const int y  = (bid / 12) % H_Y;
    const int b  = bid / (12 * H_Y);
    const int x0 = xr * 16;
    const int width = (x0 + 16 <= W_X) ? 16 : (W_X - x0);
    const int tid = threadIdx.x;

    __shared__ float tile[16][C_IN + 1];
    __shared__ int m16[16];

    if (tid < 16) m16[tid] = (tid < width) ? inv[(b * H_Y + y) * W_X + x0 + tid] : -1;
    __syncthreads();

    #pragma unroll
    for (int pass = 0; pass < 8; ++pass) {
        const int xi = pass * 2 + (tid >> 7);
        const int c  = tid & 127;
        const int m  = m16[xi];
        tile[xi][c] = (m >= 0) ? featbuf[(size_t)m * C_IN + c] : 0.0f;
    }
    __syncthreads();

    #pragma unroll
    for (int pass = 0; pass < 8; ++pass) {
        const int c  = pass * 16 + (tid >> 4);
        const int xi = tid & 15;
        if (xi < width)
            out[(((size_t)b * C_IN + c) * H_Y + y) * W_X + x0 + xi] = tile[xi][c];
    }
}

// ---- MFMA pre-attention + t-precompute: 16 queries / 256-thread block.
//   sc = gelu(bev@w_bev^T+b); qln = LN(sc); qh = qln@wq^T+bq;
//   t[h] = qh_h @ wk_h  -> pack row as bf16[512];  tbv[h] = qh_h.bk_h -> tbvbuf.
__global__ __launch_bounds__(256) void k_pre(
    float* __restrict__ pack, const ushort* __restrict__ wbev_s,
    const float* __restrict__ b_bev, const float* __restrict__ g_q,
    const float* __restrict__ be_q, const ushort* __restrict__ wq_s,
    const ushort* __restrict__ wkt_s, const float* __restrict__ b_in,
    float* __restrict__ sc_g, float* __restrict__ tbvbuf, const int M)
{
    __shared__ ushort bevl16[16][C_BEV + 8];
    __shared__ float  scl[16][C_IN];           // sc, then qh (f32)
    __shared__ ushort qlnl16[16][C_IN + 8];
    __shared__ ushort qhl16[16][C_IN + 8];     // qh bf16 (A for t-GEMM)
    __shared__ ushort tl16[16][N_H][C_IN];     // t output
    const int tid = threadIdx.x;
    const int m16 = blockIdx.x * 16;
    const int wave = tid >> 6, lane = tid & 63;
    const int llo = lane & 15, lhi = lane >> 4;
    const int qs = tid >> 4, seg = tid & 15;
    int mq = m16 + qs; if (mq >= M) mq = M - 1;

    {
        const float4* srcp = (const float4*)(pack + (size_t)mq * C_BEV + seg * 16);
        ushort tmp[16];
        #pragma unroll
        for (int j4 = 0; j4 < 4; ++j4) {
            const float4 v = srcp[j4];
            tmp[j4*4+0] = f2bf(v.x); tmp[j4*4+1] = f2bf(v.y);
            tmp[j4*4+2] = f2bf(v.z); tmp[j4*4+3] = f2bf(v.w);
        }
        short8* d = (short8*)&bevl16[qs][seg * 16];
        d[0] = *(short8*)&tmp[0];
        d[1] = *(short8*)&tmp[8];
    }
    __syncthreads();                                  // B1

    {   // sc GEMM 16x128x256
        f32x4 acc0 = {0.f,0.f,0.f,0.f}, acc1 = {0.f,0.f,0.f,0.f};
        #pragma unroll
        for (int kt = 0; kt < 8; ++kt) {
            const short8 a = *(const short8*)&bevl16[llo][kt*32 + lhi*8];
            const short8 b0 = *(const short8*)&wbev_s[(size_t)(((wave    )*8 + kt)*64 + lane)*8];
            const short8 b1 = *(const short8*)&wbev_s[(size_t)(((wave + 4)*8 + kt)*64 + lane)*8];
            acc0 = __builtin_amdgcn_mfma_f32_16x16x32_bf16(a, b0, acc0, 0, 0, 0);
            acc1 = __builtin_amdgcn_mfma_f32_16x16x32_bf16(a, b1, acc1, 0, 0, 0);
        }
        #pragma unroll
        for (int qe = 0; qe < 4; ++qe) {
            const int row = lhi * 4 + qe;
            const int c0 = wave * 16 + llo, c1 = (wave + 4) * 16 + llo;
            scl[row][c0] = gelu_exact(acc0[qe] + b_bev[c0]);
            scl[row][c1] = gelu_exact(acc1[qe] + b_bev[c1]);
        }
    }
    __syncthreads();                                  // B2

    {   // sc_g write + LN -> qlnl16
        float* dst = sc_g + (size_t)mq * C_IN + seg * 8;
        float v[8];
        #pragma unroll
        for (int j = 0; j < 8; ++j) v[j] = scl[qs][seg * 8 + j];
        *(float4*)&dst[0] = make_float4(v[0], v[1], v[2], v[3]);
        *(float4*)&dst[4] = make_float4(v[4], v[5], v[6], v[7]);

        float s = 0.f;
        #pragma unroll
        for (int j = 0; j < 8; ++j) s += v[j];
        s += __shfl_xor(s, 1); s += __shfl_xor(s, 2);
        s += __shfl_xor(s, 4); s += __shfl_xor(s, 8);
        const float mean = s * (1.0f / 128.0f);
        float vv = 0.f;
        #pragma unroll
        for (int j = 0; j < 8; ++j) { const float d = v[j] - mean; vv += d * d; }
        vv += __shfl_xor(vv, 1); vv += __shfl_xor(vv, 2);
        vv += __shfl_xor(vv, 4); vv += __shfl_xor(vv, 8);
        const float rs = rsqrtf(vv * (1.0f / 128.0f) + 1e-5f);
        #pragma unroll
        for (int j = 0; j < 8; ++j) {
            const int c = seg * 8 + j;
            qlnl16[qs][c] = f2bf((v[j] - mean) * rs * g_q[c] + be_q[c]);
        }
    }
    __syncthreads();                                  // B3

    {   // qh GEMM 16x128x128 -> scl (f32) + qhl16 (bf16)
        f32x4 acc0 = {0.f,0.f,0.f,0.f}, acc1 = {0.f,0.f,0.f,0.f};
        #pragma unroll
        for (int kt = 0; kt < 4; ++kt) {
            const short8 a = *(const short8*)&qlnl16[llo][kt*32 + lhi*8];
            const short8 b0 = *(const short8*)&wq_s[(size_t)(((wave    )*4 + kt)*64 + lane)*8];
            const short8 b1 = *(const short8*)&wq_s[(size_t)(((wave + 4)*4 + kt)*64 + lane)*8];
            acc0 = __builtin_amdgcn_mfma_f32_16x16x32_bf16(a, b0, acc0, 0, 0, 0);
            acc1 = __builtin_amdgcn_mfma_f32_16x16x32_bf16(a, b1, acc1, 0, 0, 0);
        }
        #pragma unroll
        for (int qe = 0; qe < 4; ++qe) {
            const int row = lhi * 4 + qe;
            const int c0 = wave * 16 + llo, c1 = (wave + 4) * 16 + llo;
            const float v0 = acc0[qe] + b_in[c0];
            const float v1 = acc1[qe] + b_in[c1];
            scl[row][c0] = v0;  qhl16[row][c0] = f2bf(v0);
            scl[row][c1] = v1;  qhl16[row][c1] = f2bf(v1);
        }
    }
    __syncthreads();                                  // B4

    {   // t GEMM: per head K=32; wave does ct in {wave, wave+4}
        #pragma unroll
        for (int h = 0; h < N_H; ++h) {
            const short8 a = *(const short8*)&qhl16[llo][h*32 + lhi*8];
            #pragma unroll
            for (int cti = 0; cti < 2; ++cti) {
                const int ct = wave + cti * 4;
                const short8 b = *(const short8*)&wkt_s[(size_t)(((h*8 + ct)*64 + lane))*8];
                f32x4 acc = {0.f,0.f,0.f,0.f};
                acc = __builtin_amdgcn_mfma_f32_16x16x32_bf16(a, b, acc, 0, 0, 0);
                #pragma unroll
                for (int qe = 0; qe < 4; ++qe)
                    tl16[lhi*4 + qe][h][ct*16 + llo] = f2bf(acc[qe]);
            }
        }
    }
    __syncthreads();                                  // B5

    {   // t -> pack row (512 bf16, coalesced 32/thread) + tbv
        ushort* dstu = (ushort*)(pack + (size_t)mq * C_BEV);
        const ushort* srcu = &tl16[qs][0][0];
        #pragma unroll
        for (int j8 = 0; j8 < 4; ++j8)
            *(short8*)&dstu[seg*32 + j8*8] = *(const short8*)&srcu[seg*32 + j8*8];

        const int h = seg >> 2, quarter = seg & 3;
        float part = 0.f;
        #pragma unroll
        for (int j = 0; j < 8; ++j) {
            const int d = h*32 + quarter*8 + j;
            part += scl[qs][d] * b_in[C_IN + d];
        }
        part += __shfl_xor(part, 1);
        part += __shfl_xor(part, 2);
        if (quarter == 0) tbvbuf[(size_t)mq * 4 + h] = part;
    }
}

// ---- attention kernel: 2q/512t. t precomputed (no qh/t-phase).
__global__ __launch_bounds__(512) void k_attn(
    const float* __restrict__ vf, const int* __restrict__ spi,
    const int* __restrict__ ni, const int* __restrict__ kidx,
    float* __restrict__ pack, const float* __restrict__ tbvbuf,
    const float* __restrict__ w_pos, const float* __restrict__ b_pos,
    const float* __restrict__ g_k, const float* __restrict__ be_k,
    const float* __restrict__ w_in, const float* __restrict__ b_in,
    const int M)
{
    const int tid = threadIdx.x;
    const int m2 = blockIdx.x * 2;
    const int mA = m2;
    const int mB = (m2 + 1 < M) ? (m2 + 1) : (M - 1);

    __shared__ ushort kf16[64][C_IN + 8];
    __shared__ float tk[2 * 4 * C_IN];       // t (f32), then kbar
    __shared__ float attnw[2 * 4 * NKEY];
    __shared__ float tbvs[8];
    __shared__ int   kmsk[64];
    __shared__ int   kvs[64];
    __shared__ int   lst[64];
    __shared__ int   cntS;
    __shared__ float prm[768];   // w_pos[384] | b_pos[128] | g_k[128] | be_k[128]

    const int nxA = ni[mA*4+3], nyA = ni[mA*4+2];
    const int nxB = ni[mB*4+3], nyB = ni[mB*4+2];

    // stage params + t (bf16->f32) + tbv + masks/compact-list
    for (int i = tid; i < 768; i += 512) {
        float val;
        if (i < 384)      val = w_pos[i];
        else if (i < 512) val = b_pos[i - 384];
        else if (i < 640) val = g_k[i - 512];
        else              val = be_k[i - 640];
        prm[i] = val;
    }
    {
        const int q = tid >> 8, rem = tid & 255;
        const uint u = ((const uint*)(pack + (size_t)(q ? mB : mA) * C_BEV))[rem];
        tk[q*512 + rem*2]     = bf2f((ushort)(u & 0xffff));
        tk[q*512 + rem*2 + 1] = bf2f((ushort)(u >> 16));
    }
    if (tid < 8) tbvs[tid] = tbvbuf[(size_t)((tid >> 2) ? mB : mA) * 4 + (tid & 3)];
    if (tid < 64) {
        const int qk = tid >> 5;
        const int kv = kidx[(size_t)(qk ? mB : mA) * NKEY + (tid & 31)];
        const bool act = (kv >= 0);
        kmsk[tid] = act ? 0 : 1;
        kvs[tid]  = act ? kv : 0;
        const unsigned long long bal = __ballot(act);
        if (tid == 0) cntS = (int)__popcll(bal);
        if (act) lst[(int)__popcll(bal & ((1ull << tid) - 1ull))] = tid;
    }
    __syncthreads();                                  // B1

    // P1: zero masked rows; gather+posemb+LN only for active rows (compacted)
    {
        const int grp = tid >> 3, g = tid & 7, c0 = g * 16;
        if (kmsk[grp]) {
            const short8 z = (short8){0,0,0,0,0,0,0,0};
            short8* d = (short8*)&kf16[grp][c0];
            d[0] = z; d[1] = z;
        }
        if (grp < cntS) {
            const int kk = lst[grp];
            const int qk = kk >> 5;
            const int safe = kvs[kk];
            const int nxk = qk ? nxB : nxA, nyk = qk ? nyB : nyA;
            const float qxk = (nxk + 0.5f) * (150.4f / 180.0f) - 75.2f;
            const float qyk = (nyk + 0.5f) * (150.4f / 180.0f) - 75.2f;
            const int sz = spi[safe * 4 + 1];
            const int sy = spi[safe * 4 + 2];
            const int sx = spi[safe * 4 + 3];
            const float cx = (sx + 0.5f) * (150.4f / 1440.0f) - 75.2f - qxk;
            const float cy = (sy + 0.5f) * (150.4f / 1440.0f) - 75.2f - qyk;
            const float cz = (sz + 0.5f) * (6.0f / 40.0f)     - 3.0f;

            float v[16];
            const float4* src = (const float4*)(vf + (size_t)safe * C_IN + c0);
            #pragma unroll
            for (int j = 0; j < 4; ++j) {
                float4 t = src[j];
                v[j*4+0] = t.x; v[j*4+1] = t.y; v[j*4+2] = t.z; v[j*4+3] = t.w;
            }
            #pragma unroll
            for (int ch = 0; ch < 2; ++ch) {
                const int cb = c0 + ch * 8;
                float wpl[24];
                const float4* wpr = (const float4*)&prm[cb * 3];
                #pragma unroll
                for (int j4 = 0; j4 < 6; ++j4) *(float4*)&wpl[j4*4] = wpr[j4];
                float bpl[8];
                *(float4*)&bpl[0] = *(const float4*)&prm[384 + cb];
                *(float4*)&bpl[4] = *(const float4*)&prm[384 + cb + 4];
                #pragma unroll
                for (int j = 0; j < 8; ++j) {
                    const float e = cx*wpl[j*3+0] + cy*wpl[j*3+1] + cz*wpl[j*3+2] + bpl[j];
                    v[ch*8+j] += gelu_exact(e);
                }
            }
            float s = 0.f;
            #pragma unroll
            for (int j = 0; j < 16; ++j) s += v[j];
            s += __shfl_xor(s, 1); s += __shfl_xor(s, 2); s += __shfl_xor(s, 4);
            const float mean = s * (1.0f / 128.0f);
            float vv = 0.f;
            #pragma unroll
            for (int j = 0; j < 16; ++j) { const float d = v[j] - mean; vv += d * d; }
            vv += __shfl_xor(vv, 1); vv += __shfl_xor(vv, 2); vv += __shfl_xor(vv, 4);
            const float rs = rsqrtf(vv * (1.0f / 128.0f) + 1e-5f);
            ushort o[16];
            #pragma unroll
            for (int ch = 0; ch < 2; ++ch) {
                const int cb = c0 + ch * 8;
                float gkl[8], bel[8];
                *(float4*)&gkl[0] = *(const float4*)&prm[512 + cb];
                *(float4*)&gkl[4] = *(const float4*)&prm[512 + cb + 4];
                *(float4*)&bel[0] = *(const float4*)&prm[640 + cb];
                *(float4*)&bel[4] = *(const float4*)&prm[640 + cb + 4];
                #pragma unroll
                for (int j = 0; j < 8; ++j)
                    o[ch*8+j] = f2bf((v[ch*8+j] - mean) * rs * gkl[j] + bel[j]);
            }
            short8* drow = (short8*)(&kf16[kk][c0]);
            drow[0] = *(short8*)&o[0];
            drow[1] = *(short8*)&o[8];
        }
    }
    __syncthreads();                                  // B2

    // logits + masked softmax (t from tk; tbv from LDS)
    {
        const int q = tid >> 8, r = tid & 255;
        const int h = r >> 6, half = (r >> 5) & 1, p = r & 31;
        const float* tr = &tk[(q*4 + h)*128 + half*64];
        const ushort* kr = &kf16[q*NKEY + p][half*64];
        float d = 0.f;
        #pragma unroll
        for (int c2 = 0; c2 < 32; ++c2) {
            const uint u = *(const uint*)&kr[c2*2];
            d += tr[c2*2]   * bf2f((ushort)(u & 0xffff));
            d += tr[c2*2+1] * bf2f((ushort)(u >> 16));
        }
        d += __shfl_xor(d, 32);
        const int msk = kmsk[q*NKEY + p];
        float logit = msk ? -3.0e38f : (d + tbvs[q*4 + h]) * 0.17677669529663687f;
        float mx = logit;
        #pragma unroll
        for (int o = 16; o >= 1; o >>= 1) mx = fmaxf(mx, __shfl_xor(mx, o));
        const float e = msk ? 0.0f : expf(logit - mx);
        float ssum = e;
        #pragma unroll
        for (int o = 16; o >= 1; o >>= 1) ssum += __shfl_xor(ssum, o);
        if (half == 0) attnw[(q*4 + h)*32 + p] = e / ssum;
    }
    __syncthreads();                                  // B3

    // kbar (overwrites tk; masked rows are zeros)
    {
        const int q = tid >> 8, r = tid & 255;
        const int c = r & 127, h2 = r >> 7;
        #pragma unroll
        for (int hi = 0; hi < 2; ++hi) {
            const int hh = h2 + 2 * hi;
            float acc = 0.f;
            #pragma unroll
            for (int p = 0; p < NKEY; ++p)
                acc += attnw[(q*4 + hh)*32 + p] * bf2f(kf16[q*NKEY + p][c]);
            tk[(q*4 + hh)*128 + c] = acc;
        }
    }
    __syncthreads();                                  // B4

    // av -> pack[m][128:256) (t dead; safe overwrite)
    {
        const int wave = tid >> 6, lane = tid & 63;
        #pragma unroll 4
        for (int t = wave; t < 128; t += 8) {
            const int row = t * 2 + (lane >> 5);
            const int q = row >> 7, j = row & 127;
            const int h = j >> 5;
            const float4 w4 = ((const float4*)(w_in + (size_t)(2*C_IN + j) * C_IN))[lane & 31];
            const float4 k4 = ((const float4*)&tk[(q*4 + h)*128])[lane & 31];
            float a = dot4(w4, k4);
            a += __shfl_xor(a, 1); a += __shfl_xor(a, 2); a += __shfl_xor(a, 4);
            a += __shfl_xor(a, 8); a += __shfl_xor(a, 16);
            if ((lane & 31) == 0 && (m2 + q) < M)
                pack[(size_t)(q ? mB : mA) * C_BEV + C_IN + j] = a + b_in[2*C_IN + j];
        }
    }
}

// ---- MFMA post-attention (verified R21): 16 queries / 256-thread block.
__global__ __launch_bounds__(256) void k_post(
    const float* __restrict__ pack,
    const ushort* __restrict__ wout_s, const float* __restrict__ b_out,
    const float* __restrict__ g_f, const float* __restrict__ be_f,
    const ushort* __restrict__ wfc1_s, const float* __restrict__ b_fc1,
    const ushort* __restrict__ wfc2_s, const float* __restrict__ b_fc2,
    float* __restrict__ scfeat, const int M)
{
    __shared__ ushort avl16[16][C_IN + 8];
    __shared__ float  sclp[16][C_IN];
    __shared__ float  xfl[16][C_IN];
    __shared__ ushort ylnl16[16][C_IN + 8];
    __shared__ ushort h1l16[16][C_IN + 8];
    const int tid = threadIdx.x;
    const int m16 = blockIdx.x * 16;
    const int wave = tid >> 6, lane = tid & 63;
    const int llo = lane & 15, lhi = lane >> 4;
    const int qs = tid >> 4, seg = tid & 15;
    int mq = m16 + qs; if (mq >= M) mq = M - 1;

    {
        const float4* ap = (const float4*)(pack + (size_t)mq * C_BEV + C_IN + seg * 8);
        const float4 a0 = ap[0], a1 = ap[1];
        ushort tmp[8];
        tmp[0]=f2bf(a0.x); tmp[1]=f2bf(a0.y); tmp[2]=f2bf(a0.z); tmp[3]=f2bf(a0.w);
        tmp[4]=f2bf(a1.x); tmp[5]=f2bf(a1.y); tmp[6]=f2bf(a1.z); tmp[7]=f2bf(a1.w);
        *(short8*)&avl16[qs][seg * 8] = *(short8*)&tmp[0];
        const float4* sp = (const float4*)(scfeat + (size_t)mq * C_IN + seg * 8);
        *(float4*)&sclp[qs][seg * 8]     = sp[0];
        *(float4*)&sclp[qs][seg * 8 + 4] = sp[1];
    }
    __syncthreads();

    {
        f32x4 acc0 = {0.f,0.f,0.f,0.f}, acc1 = {0.f,0.f,0.f,0.f};
        #pragma unroll
        for (int kt = 0; kt < 4; ++kt) {
            const short8 a = *(const short8*)&avl16[llo][kt*32 + lhi*8];
            const short8 b0 = *(const short8*)&wout_s[(size_t)(((wave    )*4 + kt)*64 + lane)*8];
            const short8 b1 = *(const short8*)&wout_s[(size_t)(((wave + 4)*4 + kt)*64 + lane)*8];
            acc0 = __builtin_amdgcn_mfma_f32_16x16x32_bf16(a, b0, acc0, 0, 0, 0);
            acc1 = __builtin_amdgcn_mfma_f32_16x16x32_bf16(a, b1, acc1, 0, 0, 0);
        }
        #pragma unroll
        for (int qe = 0; qe < 4; ++qe) {
            const int row = lhi * 4 + qe;
            const int c0 = wave * 16 + llo, c1 = (wave + 4) * 16 + llo;
            xfl[row][c0] = acc0[qe] + b_out[c0] + sclp[row][c0];
            xfl[row][c1] = acc1[qe] + b_out[c1] + sclp[row][c1];
        }
    }
    __syncthreads();

    {
        float v[8];
        #pragma unroll
        for (int j = 0; j < 8; ++j) v[j] = xfl[qs][seg * 8 + j];
        float s = 0.f;
        #pragma unroll
        for (int j = 0; j < 8; ++j) s += v[j];
        s += __shfl_xor(s, 1); s += __shfl_xor(s, 2);
        s += __shfl_xor(s, 4); s += __shfl_xor(s, 8);
        const float mean = s * (1.0f / 128.0f);
        float vv = 0.f;
        #pragma unroll
        for (int j = 0; j < 8; ++j) { const float d = v[j] - mean; vv += d * d; }
        vv += __shfl_xor(vv, 1); vv += __shfl_xor(vv, 2);
        vv += __shfl_xor(vv, 4); vv += __shfl_xor(vv, 8);
        const float rs = rsqrtf(vv * (1.0f / 128.0f) + 1e-5f);
        #pragma unroll
        for (int j = 0; j < 8; ++j) {
            const int c = seg * 8 + j;
            ylnl16[qs][c] = f2bf((v[j] - mean) * rs * g_f[c] + be_f[c]);
        }
    }
    __syncthreads();

    {
        f32x4 acc0 = {0.f,0.f,0.f,0.f}, acc1 = {0.f,0.f,0.f,0.f};
        #pragma unroll
        for (int kt = 0; kt < 4; ++kt) {
            const short8 a = *(const short8*)&ylnl16[llo][kt*32 + lhi*8];
            const short8 b0 = *(const short8*)&wfc1_s[(size_t)(((wave    )*4 + kt)*64 + lane)*8];
            const short8 b1 = *(const short8*)&wfc1_s[(size_t)(((wave + 4)*4 + kt)*64 + lane)*8];
            acc0 = __builtin_amdgcn_mfma_f32_16x16x32_bf16(a, b0, acc0, 0, 0, 0);
            acc1 = __builtin_amdgcn_mfma_f32_16x16x32_bf16(a, b1, acc1, 0, 0, 0);
        }
        #pragma unroll
        for (int qe = 0; qe < 4; ++qe) {
            const int row = lhi * 4 + qe;
            const int c0 = wave * 16 + llo, c1 = (wave + 4) * 16 + llo;
            h1l16[row][c0] = f2bf(gelu_exact(acc0[qe] + b_fc1[c0]));
            h1l16[row][c1] = f2bf(gelu_exact(acc1[qe] + b_fc1[c1]));
        }
    }
    __syncthreads();

    {
        f32x4 acc0 = {0.f,0.f,0.f,0.f}, acc1 = {0.f,0.f,0.f,0.f};
        #pragma unroll
        for (int kt = 0; kt < 4; ++kt) {
            const short8 a = *(const short8*)&h1l16[llo][kt*32 + lhi*8];
            const short8 b0 = *(const short8*)&wfc2_s[(size_t)(((wave    )*4 + kt)*64 + lane)*8];
            const short8 b1 = *(const short8*)&wfc2_s[(size_t)(((wave + 4)*4 + kt)*64 + lane)*8];
            acc0 = __builtin_amdgcn_mfma_f32_16x16x32_bf16(a, b0, acc0, 0, 0, 0);
            acc1 = __builtin_amdgcn_mfma_f32_16x16x32_bf16(a, b1, acc1, 0, 0, 0);
        }
        #pragma unroll
        for (int qe = 0; qe < 4; ++qe) {
            const int row = lhi * 4 + qe;
            const int c0 = wave * 16 + llo, c1 = (wave + 4) * 16 + llo;
            sclp[row][c0] = acc0[qe] + b_fc2[c0] + xfl[row][c0];
            sclp[row][c1] = acc1[qe] + b_fc2[c1] + xfl[row][c1];
        }
    }
    __syncthreads();

    {
        float* dst = scfeat + (size_t)mq * C_IN + seg * 8;
        *(float4*)&dst[0] = make_float4(sclp[qs][seg*8+0], sclp[qs][seg*8+1],
                                        sclp[qs][seg*8+2], sclp[qs][seg*8+3]);
        *(float4*)&dst[4] = make_float4(sclp[qs][seg*8+4], sclp[qs][seg*8+5],
                                        sclp[qs][seg*8+6], sclp[qs][seg*8+7]);
    }
}

extern "C" void kernel_launch(void* const* d_in, const int* in_sizes, int n_in,
                              void* d_out, int out_size, void* d_ws, size_t ws_size,
                              hipStream_t stream) {
    const float* vf    = (const float*)d_in[0];
    const int*   spi   = (const int*)  d_in[1];
    const int*   ni    = (const int*)  d_in[2];
    const int*   kidx  = (const int*)  d_in[3];
    const float* bev   = (const float*)d_in[4];
    const float* w_pos = (const float*)d_in[5];
    const float* b_pos = (const float*)d_in[6];
    const float* w_bev = (const float*)d_in[7];
    const float* b_bev = (const float*)d_in[8];
    const float* g_q   = (const float*)d_in[9];
    const float* be_q  = (const float*)d_in[10];
    const float* g_k   = (const float*)d_in[11];
    const float* be_k  = (const float*)d_in[12];
    const float* g_f   = (const float*)d_in[13];
    const float* be_f  = (const float*)d_in[14];
    const float* w_in  = (const float*)d_in[15];
    const float* b_in  = (const float*)d_in[16];
    const float* w_out = (const float*)d_in[17];
    const float* b_out = (const float*)d_in[18];
    const float* w_fc1 = (const float*)d_in[19];
    const float* b_fc1 = (const float*)d_in[20];
    const float* w_fc2 = (const float*)d_in[21];
    const float* b_fc2 = (const float*)d_in[22];
    float* out = (float*)d_out;

    const int M = in_sizes[3] / NKEY;

    // ---- workspace:
    //  inv    @0      ; tbvbuf @2MiB ; pack @4MiB ([M][256] f32)
    //  scfeat @34MiB  ; swizzled weights @49MiB (wbev 64K|wq 32K|wout 32K|wfc1 32K|wfc2 32K|wkt 32K)
    char* ws = (char*)d_ws;
    const size_t MiB = 1u << 20;
    int*    inv    = (int*)ws;
    float*  tbvbuf = (float*)(ws + 2 * MiB);
    float*  pack   = (float*)(ws + 4 * MiB);
    float*  scfeat = (float*)(ws + 34 * MiB);
    ushort* wbev_s = (ushort*)(ws + 49 * MiB);
    ushort* wq_s   = wbev_s + 128 * 256;
    ushort* wout_s = wq_s   + 128 * 128;
    ushort* wfc1_s = wout_s + 128 * 128;
    ushort* wfc2_s = wfc1_s + 128 * 128;
    ushort* wkt_s  = wfc2_s + 128 * 128;

    hipMemsetAsync(inv, 0xFF, (size_t)4 * H_Y * W_X * sizeof(int), stream);
    build_inv<<<(M + 255) / 256, 256, 0, stream>>>(ni, inv, M);

    conv_swz<<<128, 256, 0, stream>>>(w_bev, wbev_s, C_BEV, 128 * 256);
    conv_swz<<<64, 256, 0, stream>>>(w_in,  wq_s,   C_IN, 128 * 128);
    conv_swz<<<64, 256, 0, stream>>>(w_out, wout_s, C_IN, 128 * 128);
    conv_swz<<<64, 256, 0, stream>>>(w_fc1, wfc1_s, C_IN, 128 * 128);
    conv_swz<<<64, 256, 0, stream>>>(w_fc2, wfc2_s, C_IN, 128 * 128);
    conv_swz_t<<<64, 256, 0, stream>>>(w_in, wkt_s);

    compact_bev<<<4 * H_Y * 12, 256, 0, stream>>>(bev, inv, pack);

    k_pre<<<(M + 15) / 16, 256, 0, stream>>>(pack, wbev_s, b_bev, g_q, be_q,
                                             wq_s, wkt_s, b_in, scfeat, tbvbuf, M);
    k_attn<<<(M + 1) / 2, 512, 0, stream>>>(vf, spi, ni, kidx, pack, tbvbuf,
                                            w_pos, b_pos, g_k, be_k, w_in, b_in, M);
    k_post<<<(M + 15) / 16, 256, 0, stream>>>(pack, wout_s, b_out, g_f, be_f,
                                              wfc1_s, b_fc1, wfc2_s, b_fc2, scfeat, M);

    write_out_t<<<4 * H_Y * 12, 256, 0, stream>>>(inv, scfeat, out);
}

// Round 24
// 461.806 us; speedup vs baseline: 3.7359x; 1.3681x over previous
//
#include <hip/hip_runtime.h>
#include <hip/hip_bf16.h>
#include <cmath>

#define C_IN 128
#define NKEY 32
#define N_H 4
#define D_H 32
#define C_BEV 256
#define H_Y 180
#define W_X 180

typedef __attribute__((ext_vector_type(8))) short short8;
typedef __attribute__((ext_vector_type(4))) float f32x4;

// tanh-form GELU via hw exp: |err vs exact erf-GELU| < 4e-4 (below bf16 rounding).
// 0.5x(1+tanh(y)) == x*e^{2y}/(e^{2y}+1); clamp avoids inf/inf NaN for |x|>~11.
__device__ __forceinline__ float gelu_fast(float x) {
    const float y2 = fminf(1.5957691216057308f * (x + 0.044715f * x * x * x), 80.0f);
    const float e = __expf(y2);
    return x * e / (e + 1.0f);
}
__device__ __forceinline__ float dot4(float4 a, float4 b) {
    return a.x * b.x + a.y * b.y + a.z * b.z + a.w * b.w;
}
__device__ __forceinline__ float bf2f(ushort u) {
    union { unsigned int i; float f; } c; c.i = ((unsigned int)u) << 16; return c.f;
}
__device__ __forceinline__ ushort f2bf(float x) {
    __hip_bfloat16 h = __float2bfloat16(x);
    return *reinterpret_cast<ushort*>(&h);
}

// ---- one-time: f32 weight [OUT][K] -> bf16 MFMA fragment order (verified R21)
__global__ void conv_swz(const float* __restrict__ src, ushort* __restrict__ dst,
                         int K, int total) {
    const int idx = blockIdx.x * 256 + threadIdx.x;
    if (idx < total) {
        const int j = idx & 7;
        const int t8 = idx >> 3;
        const int lane = t8 & 63;
        const int tile = t8 >> 6;
        const int NK = K >> 5;
        const int kt = tile % NK, ct = tile / NK;
        const int row = ct * 16 + (lane & 15);
        const int k = kt * 32 + (lane >> 4) * 8 + j;
        dst[idx] = f2bf(src[(size_t)row * K + k]);
    }
}

// ---- one-time: wk^T per head -> fragment order for t-GEMM (verified R23)
__global__ void conv_swz_t(const float* __restrict__ w_in, ushort* __restrict__ dst) {
    const int idx = blockIdx.x * 256 + threadIdx.x;   // 16384
    if (idx < 16384) {
        const int j = idx & 7;
        const int lane = (idx >> 3) & 63;
        const int tile = idx >> 9;
        const int ct = tile & 7, h = tile >> 3;
        const int row_w = 128 + h * 32 + (lane >> 4) * 8 + j;
        const int col = ct * 16 + (lane & 15);
        dst[idx] = f2bf(w_in[(size_t)row_w * C_IN + col]);
    }
}

// ---- inv[cell] = m  (inv pre-memset to -1)
__global__ void build_inv(const int* __restrict__ ni, int* __restrict__ inv, int M) {
    const int m = blockIdx.x * 256 + threadIdx.x;
    if (m < M) {
        const int b = ni[m*4+0], y = ni[m*4+2], x = ni[m*4+3];
        inv[(b * H_Y + y) * W_X + x] = m;
    }
}

// ---- compact bev -> pack[m][0:256] contiguous (verified R8/R13)
__global__ __launch_bounds__(256) void compact_bev(
    const float* __restrict__ bev, const int* __restrict__ inv,
    float* __restrict__ pack)
{
    const int bid = blockIdx.x;
    const int xr = bid % 12;
    const int y  = (bid / 12) % H_Y;
    const int b  = bid / (12 * H_Y);
    const int x0 = xr * 16;
    const int width = (x0 + 16 <= W_X) ? 16 : (W_X - x0);
    const int tid = threadIdx.x;

    __shared__ float tile[16][257];

    const int xq = (tid & 3) * 4;
    #pragma unroll
    for (int p = 0; p < 4; ++p) {
        const int c = p * 64 + (tid >> 2);
        if (xq < width) {
            const float4 v = *(const float4*)(bev +
                (((size_t)b * C_BEV + c) * H_Y + y) * W_X + x0 + xq);
            tile[xq+0][c] = v.x; tile[xq+1][c] = v.y;
            tile[xq+2][c] = v.z; tile[xq+3][c] = v.w;
        }
    }
    __syncthreads();
    for (int xi = 0; xi < width; ++xi) {
        const int m = inv[(b * H_Y + y) * W_X + x0 + xi];
        if (m >= 0) pack[(size_t)m * C_BEV + tid] = tile[xi][tid];
    }
}

// ---- transposed write-out (verified R19)
__global__ __launch_bounds__(256) void write_out_t(
    const int* __restrict__ inv, const float* __restrict__ featbuf,
    float* __restrict__ out)
{
    const int bid = blockIdx.x;
    const int xr = bid % 12;
    const int y  = (bid / 12) % H_Y;
    const int b  = bid / (12 * H_Y);
    const int x0 = xr * 16;
    const int width = (x0 + 16 <= W_X) ? 16 : (W_X - x0);
    const int tid = threadIdx.x;

    __shared__ float tile[16][C_IN + 1];
    __shared__ int m16[16];

    if (tid < 16) m16[tid] = (tid < width) ? inv[(b * H_Y + y) * W_X + x0 + tid] : -1;
    __syncthreads();

    #pragma unroll
    for (int pass = 0; pass < 8; ++pass) {
        const int xi = pass * 2 + (tid >> 7);
        const int c  = tid & 127;
        const int m  = m16[xi];
        tile[xi][c] = (m >= 0) ? featbuf[(size_t)m * C_IN + c] : 0.0f;
    }
    __syncthreads();

    #pragma unroll
    for (int pass = 0; pass < 8; ++pass) {
        const int c  = pass * 16 + (tid >> 4);
        const int xi = tid & 15;
        if (xi < width)
            out[(((size_t)b * C_IN + c) * H_Y + y) * W_X + x0 + xi] = tile[xi][c];
    }
}

// ---- MFMA pre-attention + t-precompute (verified R23): 16 queries / 256 threads.
__global__ __launch_bounds__(256) void k_pre(
    float* __restrict__ pack, const ushort* __restrict__ wbev_s,
    const float* __restrict__ b_bev, const float* __restrict__ g_q,
    const float* __restrict__ be_q, const ushort* __restrict__ wq_s,
    const ushort* __restrict__ wkt_s, const float* __restrict__ b_in,
    float* __restrict__ sc_g, float* __restrict__ tbvbuf, const int M)
{
    __shared__ ushort bevl16[16][C_BEV + 8];
    __shared__ float  scl[16][C_IN];           // sc, then qh (f32)
    __shared__ ushort qlnl16[16][C_IN + 8];
    __shared__ ushort qhl16[16][C_IN + 8];     // qh bf16 (A for t-GEMM)
    __shared__ ushort tl16[16][N_H][C_IN];     // t output
    const int tid = threadIdx.x;
    const int m16 = blockIdx.x * 16;
    const int wave = tid >> 6, lane = tid & 63;
    const int llo = lane & 15, lhi = lane >> 4;
    const int qs = tid >> 4, seg = tid & 15;
    int mq = m16 + qs; if (mq >= M) mq = M - 1;

    {
        const float4* srcp = (const float4*)(pack + (size_t)mq * C_BEV + seg * 16);
        ushort tmp[16];
        #pragma unroll
        for (int j4 = 0; j4 < 4; ++j4) {
            const float4 v = srcp[j4];
            tmp[j4*4+0] = f2bf(v.x); tmp[j4*4+1] = f2bf(v.y);
            tmp[j4*4+2] = f2bf(v.z); tmp[j4*4+3] = f2bf(v.w);
        }
        short8* d = (short8*)&bevl16[qs][seg * 16];
        d[0] = *(short8*)&tmp[0];
        d[1] = *(short8*)&tmp[8];
    }
    __syncthreads();                                  // B1

    {   // sc GEMM 16x128x256
        f32x4 acc0 = {0.f,0.f,0.f,0.f}, acc1 = {0.f,0.f,0.f,0.f};
        #pragma unroll
        for (int kt = 0; kt < 8; ++kt) {
            const short8 a = *(const short8*)&bevl16[llo][kt*32 + lhi*8];
            const short8 b0 = *(const short8*)&wbev_s[(size_t)(((wave    )*8 + kt)*64 + lane)*8];
            const short8 b1 = *(const short8*)&wbev_s[(size_t)(((wave + 4)*8 + kt)*64 + lane)*8];
            acc0 = __builtin_amdgcn_mfma_f32_16x16x32_bf16(a, b0, acc0, 0, 0, 0);
            acc1 = __builtin_amdgcn_mfma_f32_16x16x32_bf16(a, b1, acc1, 0, 0, 0);
        }
        #pragma unroll
        for (int qe = 0; qe < 4; ++qe) {
            const int row = lhi * 4 + qe;
            const int c0 = wave * 16 + llo, c1 = (wave + 4) * 16 + llo;
            scl[row][c0] = gelu_fast(acc0[qe] + b_bev[c0]);
            scl[row][c1] = gelu_fast(acc1[qe] + b_bev[c1]);
        }
    }
    __syncthreads();                                  // B2

    {   // sc_g write + LN -> qlnl16
        float* dst = sc_g + (size_t)mq * C_IN + seg * 8;
        float v[8];
        #pragma unroll
        for (int j = 0; j < 8; ++j) v[j] = scl[qs][seg * 8 + j];
        *(float4*)&dst[0] = make_float4(v[0], v[1], v[2], v[3]);
        *(float4*)&dst[4] = make_float4(v[4], v[5], v[6], v[7]);

        float s = 0.f;
        #pragma unroll
        for (int j = 0; j < 8; ++j) s += v[j];
        s += __shfl_xor(s, 1); s += __shfl_xor(s, 2);
        s += __shfl_xor(s, 4); s += __shfl_xor(s, 8);
        const float mean = s * (1.0f / 128.0f);
        float vv = 0.f;
        #pragma unroll
        for (int j = 0; j < 8; ++j) { const float d = v[j] - mean; vv += d * d; }
        vv += __shfl_xor(vv, 1); vv += __shfl_xor(vv, 2);
        vv += __shfl_xor(vv, 4); vv += __shfl_xor(vv, 8);
        const float rs = rsqrtf(vv * (1.0f / 128.0f) + 1e-5f);
        #pragma unroll
        for (int j = 0; j < 8; ++j) {
            const int c = seg * 8 + j;
            qlnl16[qs][c] = f2bf((v[j] - mean) * rs * g_q[c] + be_q[c]);
        }
    }
    __syncthreads();                                  // B3

    {   // qh GEMM 16x128x128 -> scl (f32) + qhl16 (bf16)
        f32x4 acc0 = {0.f,0.f,0.f,0.f}, acc1 = {0.f,0.f,0.f,0.f};
        #pragma unroll
        for (int kt = 0; kt < 4; ++kt) {
            const short8 a = *(const short8*)&qlnl16[llo][kt*32 + lhi*8];
            const short8 b0 = *(const short8*)&wq_s[(size_t)(((wave    )*4 + kt)*64 + lane)*8];
            const short8 b1 = *(const short8*)&wq_s[(size_t)(((wave + 4)*4 + kt)*64 + lane)*8];
            acc0 = __builtin_amdgcn_mfma_f32_16x16x32_bf16(a, b0, acc0, 0, 0, 0);
            acc1 = __builtin_amdgcn_mfma_f32_16x16x32_bf16(a, b1, acc1, 0, 0, 0);
        }
        #pragma unroll
        for (int qe = 0; qe < 4; ++qe) {
            const int row = lhi * 4 + qe;
            const int c0 = wave * 16 + llo, c1 = (wave + 4) * 16 + llo;
            const float v0 = acc0[qe] + b_in[c0];
            const float v1 = acc1[qe] + b_in[c1];
            scl[row][c0] = v0;  qhl16[row][c0] = f2bf(v0);
            scl[row][c1] = v1;  qhl16[row][c1] = f2bf(v1);
        }
    }
    __syncthreads();                                  // B4

    {   // t GEMM: per head K=32; wave does ct in {wave, wave+4}
        #pragma unroll
        for (int h = 0; h < N_H; ++h) {
            const short8 a = *(const short8*)&qhl16[llo][h*32 + lhi*8];
            #pragma unroll
            for (int cti = 0; cti < 2; ++cti) {
                const int ct = wave + cti * 4;
                const short8 b = *(const short8*)&wkt_s[(size_t)(((h*8 + ct)*64 + lane))*8];
                f32x4 acc = {0.f,0.f,0.f,0.f};
                acc = __builtin_amdgcn_mfma_f32_16x16x32_bf16(a, b, acc, 0, 0, 0);
                #pragma unroll
                for (int qe = 0; qe < 4; ++qe)
                    tl16[lhi*4 + qe][h][ct*16 + llo] = f2bf(acc[qe]);
            }
        }
    }
    __syncthreads();                                  // B5

    {   // t -> pack row + tbv
        ushort* dstu = (ushort*)(pack + (size_t)mq * C_BEV);
        const ushort* srcu = &tl16[qs][0][0];
        #pragma unroll
        for (int j8 = 0; j8 < 4; ++j8)
            *(short8*)&dstu[seg*32 + j8*8] = *(const short8*)&srcu[seg*32 + j8*8];

        const int h = seg >> 2, quarter = seg & 3;
        float part = 0.f;
        #pragma unroll
        for (int j = 0; j < 8; ++j) {
            const int d = h*32 + quarter*8 + j;
            part += scl[qs][d] * b_in[C_IN + d];
        }
        part += __shfl_xor(part, 1);
        part += __shfl_xor(part, 2);
        if (quarter == 0) tbvbuf[(size_t)mq * 4 + h] = part;
    }
}

// ---- attention kernel (R23 structure; gelu_fast + __expf)
__global__ __launch_bounds__(512) void k_attn(
    const float* __restrict__ vf, const int* __restrict__ spi,
    const int* __restrict__ ni, const int* __restrict__ kidx,
    float* __restrict__ pack, const float* __restrict__ tbvbuf,
    const float* __restrict__ w_pos, const float* __restrict__ b_pos,
    const float* __restrict__ g_k, const float* __restrict__ be_k,
    const float* __restrict__ w_in, const float* __restrict__ b_in,
    const int M)
{
    const int tid = threadIdx.x;
    const int m2 = blockIdx.x * 2;
    const int mA = m2;
    const int mB = (m2 + 1 < M) ? (m2 + 1) : (M - 1);

    __shared__ ushort kf16[64][C_IN + 8];
    __shared__ float tk[2 * 4 * C_IN];       // t (f32), then kbar
    __shared__ float attnw[2 * 4 * NKEY];
    __shared__ float tbvs[8];
    __shared__ int   kmsk[64];
    __shared__ int   kvs[64];
    __shared__ int   lst[64];
    __shared__ int   cntS;
    __shared__ float prm[768];   // w_pos[384] | b_pos[128] | g_k[128] | be_k[128]

    const int nxA = ni[mA*4+3], nyA = ni[mA*4+2];
    const int nxB = ni[mB*4+3], nyB = ni[mB*4+2];

    for (int i = tid; i < 768; i += 512) {
        float val;
        if (i < 384)      val = w_pos[i];
        else if (i < 512) val = b_pos[i - 384];
        else if (i < 640) val = g_k[i - 512];
        else              val = be_k[i - 640];
        prm[i] = val;
    }
    {
        const int q = tid >> 8, rem = tid & 255;
        const uint u = ((const uint*)(pack + (size_t)(q ? mB : mA) * C_BEV))[rem];
        tk[q*512 + rem*2]     = bf2f((ushort)(u & 0xffff));
        tk[q*512 + rem*2 + 1] = bf2f((ushort)(u >> 16));
    }
    if (tid < 8) tbvs[tid] = tbvbuf[(size_t)((tid >> 2) ? mB : mA) * 4 + (tid & 3)];
    if (tid < 64) {
        const int qk = tid >> 5;
        const int kv = kidx[(size_t)(qk ? mB : mA) * NKEY + (tid & 31)];
        const bool act = (kv >= 0);
        kmsk[tid] = act ? 0 : 1;
        kvs[tid]  = act ? kv : 0;
        const unsigned long long bal = __ballot(act);
        if (tid == 0) cntS = (int)__popcll(bal);
        if (act) lst[(int)__popcll(bal & ((1ull << tid) - 1ull))] = tid;
    }
    __syncthreads();                                  // B1

    {
        const int grp = tid >> 3, g = tid & 7, c0 = g * 16;
        if (kmsk[grp]) {
            const short8 z = (short8){0,0,0,0,0,0,0,0};
            short8* d = (short8*)&kf16[grp][c0];
            d[0] = z; d[1] = z;
        }
        if (grp < cntS) {
            const int kk = lst[grp];
            const int qk = kk >> 5;
            const int safe = kvs[kk];
            const int nxk = qk ? nxB : nxA, nyk = qk ? nyB : nyA;
            const float qxk = (nxk + 0.5f) * (150.4f / 180.0f) - 75.2f;
            const float qyk = (nyk + 0.5f) * (150.4f / 180.0f) - 75.2f;
            const int sz = spi[safe * 4 + 1];
            const int sy = spi[safe * 4 + 2];
            const int sx = spi[safe * 4 + 3];
            const float cx = (sx + 0.5f) * (150.4f / 1440.0f) - 75.2f - qxk;
            const float cy = (sy + 0.5f) * (150.4f / 1440.0f) - 75.2f - qyk;
            const float cz = (sz + 0.5f) * (6.0f / 40.0f)     - 3.0f;

            float v[16];
            const float4* src = (const float4*)(vf + (size_t)safe * C_IN + c0);
            #pragma unroll
            for (int j = 0; j < 4; ++j) {
                float4 t = src[j];
                v[j*4+0] = t.x; v[j*4+1] = t.y; v[j*4+2] = t.z; v[j*4+3] = t.w;
            }
            #pragma unroll
            for (int ch = 0; ch < 2; ++ch) {
                const int cb = c0 + ch * 8;
                float wpl[24];
                const float4* wpr = (const float4*)&prm[cb * 3];
                #pragma unroll
                for (int j4 = 0; j4 < 6; ++j4) *(float4*)&wpl[j4*4] = wpr[j4];
                float bpl[8];
                *(float4*)&bpl[0] = *(const float4*)&prm[384 + cb];
                *(float4*)&bpl[4] = *(const float4*)&prm[384 + cb + 4];
                #pragma unroll
                for (int j = 0; j < 8; ++j) {
                    const float e = cx*wpl[j*3+0] + cy*wpl[j*3+1] + cz*wpl[j*3+2] + bpl[j];
                    v[ch*8+j] += gelu_fast(e);
                }
            }
            float s = 0.f;
            #pragma unroll
            for (int j = 0; j < 16; ++j) s += v[j];
            s += __shfl_xor(s, 1); s += __shfl_xor(s, 2); s += __shfl_xor(s, 4);
            const float mean = s * (1.0f / 128.0f);
            float vv = 0.f;
            #pragma unroll
            for (int j = 0; j < 16; ++j) { const float d = v[j] - mean; vv += d * d; }
            vv += __shfl_xor(vv, 1); vv += __shfl_xor(vv, 2); vv += __shfl_xor(vv, 4);
            const float rs = rsqrtf(vv * (1.0f / 128.0f) + 1e-5f);
            ushort o[16];
            #pragma unroll
            for (int ch = 0; ch < 2; ++ch) {
                const int cb = c0 + ch * 8;
                float gkl[8], bel[8];
                *(float4*)&gkl[0] = *(const float4*)&prm[512 + cb];
                *(float4*)&gkl[4] = *(const float4*)&prm[512 + cb + 4];
                *(float4*)&bel[0] = *(const float4*)&prm[640 + cb];
                *(float4*)&bel[4] = *(const float4*)&prm[640 + cb + 4];
                #pragma unroll
                for (int j = 0; j < 8; ++j)
                    o[ch*8+j] = f2bf((v[ch*8+j] - mean) * rs * gkl[j] + bel[j]);
            }
            short8* drow = (short8*)(&kf16[kk][c0]);
            drow[0] = *(short8*)&o[0];
            drow[1] = *(short8*)&o[8];
        }
    }
    __syncthreads();                                  // B2

    {
        const int q = tid >> 8, r = tid & 255;
        const int h = r >> 6, half = (r >> 5) & 1, p = r & 31;
        const float* tr = &tk[(q*4 + h)*128 + half*64];
        const ushort* kr = &kf16[q*NKEY + p][half*64];
        float d = 0.f;
        #pragma unroll
        for (int c2 = 0; c2 < 32; ++c2) {
            const uint u = *(const uint*)&kr[c2*2];
            d += tr[c2*2]   * bf2f((ushort)(u & 0xffff));
            d += tr[c2*2+1] * bf2f((ushort)(u >> 16));
        }
        d += __shfl_xor(d, 32);
        const int msk = kmsk[q*NKEY + p];
        float logit = msk ? -3.0e38f : (d + tbvs[q*4 + h]) * 0.17677669529663687f;
        float mx = logit;
        #pragma unroll
        for (int o = 16; o >= 1; o >>= 1) mx = fmaxf(mx, __shfl_xor(mx, o));
        const float e = msk ? 0.0f : __expf(logit - mx);
        float ssum = e;
        #pragma unroll
        for (int o = 16; o >= 1; o >>= 1) ssum += __shfl_xor(ssum, o);
        if (half == 0) attnw[(q*4 + h)*32 + p] = e / ssum;
    }
    __syncthreads();                                  // B3

    {
        const int q = tid >> 8, r = tid & 255;
        const int c = r & 127, h2 = r >> 7;
        #pragma unroll
        for (int hi = 0; hi < 2; ++hi) {
            const int hh = h2 + 2 * hi;
            float acc = 0.f;
            #pragma unroll
            for (int p = 0; p < NKEY; ++p)
                acc += attnw[(q*4 + hh)*32 + p] * bf2f(kf16[q*NKEY + p][c]);
            tk[(q*4 + hh)*128 + c] = acc;
        }
    }
    __syncthreads();                                  // B4

    {
        const int wave = tid >> 6, lane = tid & 63;
        #pragma unroll 4
        for (int t = wave; t < 128; t += 8) {
            const int row = t * 2 + (lane >> 5);
            const int q = row >> 7, j = row & 127;
            const int h = j >> 5;
            const float4 w4 = ((const float4*)(w_in + (size_t)(2*C_IN + j) * C_IN))[lane & 31];
            const float4 k4 = ((const float4*)&tk[(q*4 + h)*128])[lane & 31];
            float a = dot4(w4, k4);
            a += __shfl_xor(a, 1); a += __shfl_xor(a, 2); a += __shfl_xor(a, 4);
            a += __shfl_xor(a, 8); a += __shfl_xor(a, 16);
            if ((lane & 31) == 0 && (m2 + q) < M)
                pack[(size_t)(q ? mB : mA) * C_BEV + C_IN + j] = a + b_in[2*C_IN + j];
        }
    }
}

// ---- MFMA post-attention (verified R21): 16 queries / 256-thread block.
__global__ __launch_bounds__(256) void k_post(
    const float* __restrict__ pack,
    const ushort* __restrict__ wout_s, const float* __restrict__ b_out,
    const float* __restrict__ g_f, const float* __restrict__ be_f,
    const ushort* __restrict__ wfc1_s, const float* __restrict__ b_fc1,
    const ushort* __restrict__ wfc2_s, const float* __restrict__ b_fc2,
    float* __restrict__ scfeat, const int M)
{
    __shared__ ushort avl16[16][C_IN + 8];
    __shared__ float  sclp[16][C_IN];
    __shared__ float  xfl[16][C_IN];
    __shared__ ushort ylnl16[16][C_IN + 8];
    __shared__ ushort h1l16[16][C_IN + 8];
    const int tid = threadIdx.x;
    const int m16 = blockIdx.x * 16;
    const int wave = tid >> 6, lane = tid & 63;
    const int llo = lane & 15, lhi = lane >> 4;
    const int qs = tid >> 4, seg = tid & 15;
    int mq = m16 + qs; if (mq >= M) mq = M - 1;

    {
        const float4* ap = (const float4*)(pack + (size_t)mq * C_BEV + C_IN + seg * 8);
        const float4 a0 = ap[0], a1 = ap[1];
        ushort tmp[8];
        tmp[0]=f2bf(a0.x); tmp[1]=f2bf(a0.y); tmp[2]=f2bf(a0.z); tmp[3]=f2bf(a0.w);
        tmp[4]=f2bf(a1.x); tmp[5]=f2bf(a1.y); tmp[6]=f2bf(a1.z); tmp[7]=f2bf(a1.w);
        *(short8*)&avl16[qs][seg * 8] = *(short8*)&tmp[0];
        const float4* sp = (const float4*)(scfeat + (size_t)mq * C_IN + seg * 8);
        *(float4*)&sclp[qs][seg * 8]     = sp[0];
        *(float4*)&sclp[qs][seg * 8 + 4] = sp[1];
    }
    __syncthreads();

    {
        f32x4 acc0 = {0.f,0.f,0.f,0.f}, acc1 = {0.f,0.f,0.f,0.f};
        #pragma unroll
        for (int kt = 0; kt < 4; ++kt) {
            const short8 a = *(const short8*)&avl16[llo][kt*32 + lhi*8];
            const short8 b0 = *(const short8*)&wout_s[(size_t)(((wave    )*4 + kt)*64 + lane)*8];
            const short8 b1 = *(const short8*)&wout_s[(size_t)(((wave + 4)*4 + kt)*64 + lane)*8];
            acc0 = __builtin_amdgcn_mfma_f32_16x16x32_bf16(a, b0, acc0, 0, 0, 0);
            acc1 = __builtin_amdgcn_mfma_f32_16x16x32_bf16(a, b1, acc1, 0, 0, 0);
        }
        #pragma unroll
        for (int qe = 0; qe < 4; ++qe) {
            const int row = lhi * 4 + qe;
            const int c0 = wave * 16 + llo, c1 = (wave + 4) * 16 + llo;
            xfl[row][c0] = acc0[qe] + b_out[c0] + sclp[row][c0];
            xfl[row][c1] = acc1[qe] + b_out[c1] + sclp[row][c1];
        }
    }
    __syncthreads();

    {
        float v[8];
        #pragma unroll
        for (int j = 0; j < 8; ++j) v[j] = xfl[qs][seg * 8 + j];
        float s = 0.f;
        #pragma unroll
        for (int j = 0; j < 8; ++j) s += v[j];
        s += __shfl_xor(s, 1); s += __shfl_xor(s, 2);
        s += __shfl_xor(s, 4); s += __shfl_xor(s, 8);
        const float mean = s * (1.0f / 128.0f);
        float vv = 0.f;
        #pragma unroll
        for (int j = 0; j < 8; ++j) { const float d = v[j] - mean; vv += d * d; }
        vv += __shfl_xor(vv, 1); vv += __shfl_xor(vv, 2);
        vv += __shfl_xor(vv, 4); vv += __shfl_xor(vv, 8);
        const float rs = rsqrtf(vv * (1.0f / 128.0f) + 1e-5f);
        #pragma unroll
        for (int j = 0; j < 8; ++j) {
            const int c = seg * 8 + j;
            ylnl16[qs][c] = f2bf((v[j] - mean) * rs * g_f[c] + be_f[c]);
        }
    }
    __syncthreads();

    {
        f32x4 acc0 = {0.f,0.f,0.f,0.f}, acc1 = {0.f,0.f,0.f,0.f};
        #pragma unroll
        for (int kt = 0; kt < 4; ++kt) {
            const short8 a = *(const short8*)&ylnl16[llo][kt*32 + lhi*8];
            const short8 b0 = *(const short8*)&wfc1_s[(size_t)(((wave    )*4 + kt)*64 + lane)*8];
            const short8 b1 = *(const short8*)&wfc1_s[(size_t)(((wave + 4)*4 + kt)*64 + lane)*8];
            acc0 = __builtin_amdgcn_mfma_f32_16x16x32_bf16(a, b0, acc0, 0, 0, 0);
            acc1 = __builtin_amdgcn_mfma_f32_16x16x32_bf16(a, b1, acc1, 0, 0, 0);
        }
        #pragma unroll
        for (int qe = 0; qe < 4; ++qe) {
            const int row = lhi * 4 + qe;
            const int c0 = wave * 16 + llo, c1 = (wave + 4) * 16 + llo;
            h1l16[row][c0] = f2bf(gelu_fast(acc0[qe] + b_fc1[c0]));
            h1l16[row][c1] = f2bf(gelu_fast(acc1[qe] + b_fc1[c1]));
        }
    }
    __syncthreads();

    {
        f32x4 acc0 = {0.f,0.f,0.f,0.f}, acc1 = {0.f,0.f,0.f,0.f};
        #pragma unroll
        for (int kt = 0; kt < 4; ++kt) {
            const short8 a = *(const short8*)&h1l16[llo][kt*32 + lhi*8];
            const short8 b0 = *(const short8*)&wfc2_s[(size_t)(((wave    )*4 + kt)*64 + lane)*8];
            const short8 b1 = *(const short8*)&wfc2_s[(size_t)(((wave + 4)*4 + kt)*64 + lane)*8];
            acc0 = __builtin_amdgcn_mfma_f32_16x16x32_bf16(a, b0, acc0, 0, 0, 0);
            acc1 = __builtin_amdgcn_mfma_f32_16x16x32_bf16(a, b1, acc1, 0, 0, 0);
        }
        #pragma unroll
        for (int qe = 0; qe < 4; ++qe) {
            const int row = lhi * 4 + qe;
            const int c0 = wave * 16 + llo, c1 = (wave + 4) * 16 + llo;
            sclp[row][c0] = acc0[qe] + b_fc2[c0] + xfl[row][c0];
            sclp[row][c1] = acc1[qe] + b_fc2[c1] + xfl[row][c1];
        }
    }
    __syncthreads();

    {
        float* dst = scfeat + (size_t)mq * C_IN + seg * 8;
        *(float4*)&dst[0] = make_float4(sclp[qs][seg*8+0], sclp[qs][seg*8+1],
                                        sclp[qs][seg*8+2], sclp[qs][seg*8+3]);
        *(float4*)&dst[4] = make_float4(sclp[qs][seg*8+4], sclp[qs][seg*8+5],
                                        sclp[qs][seg*8+6], sclp[qs][seg*8+7]);
    }
}

extern "C" void kernel_launch(void* const* d_in, const int* in_sizes, int n_in,
                              void* d_out, int out_size, void* d_ws, size_t ws_size,
                              hipStream_t stream) {
    const float* vf    = (const float*)d_in[0];
    const int*   spi   = (const int*)  d_in[1];
    const int*   ni    = (const int*)  d_in[2];
    const int*   kidx  = (const int*)  d_in[3];
    const float* bev   = (const float*)d_in[4];
    const float* w_pos = (const float*)d_in[5];
    const float* b_pos = (const float*)d_in[6];
    const float* w_bev = (const float*)d_in[7];
    const float* b_bev = (const float*)d_in[8];
    const float* g_q   = (const float*)d_in[9];
    const float* be_q  = (const float*)d_in[10];
    const float* g_k   = (const float*)d_in[11];
    const float* be_k  = (const float*)d_in[12];
    const float* g_f   = (const float*)d_in[13];
    const float* be_f  = (const float*)d_in[14];
    const float* w_in  = (const float*)d_in[15];
    const float* b_in  = (const float*)d_in[16];
    const float* w_out = (const float*)d_in[17];
    const float* b_out = (const float*)d_in[18];
    const float* w_fc1 = (const float*)d_in[19];
    const float* b_fc1 = (const float*)d_in[20];
    const float* w_fc2 = (const float*)d_in[21];
    const float* b_fc2 = (const float*)d_in[22];
    float* out = (float*)d_out;

    const int M = in_sizes[3] / NKEY;

    char* ws = (char*)d_ws;
    const size_t MiB = 1u << 20;
    int*    inv    = (int*)ws;
    float*  tbvbuf = (float*)(ws + 2 * MiB);
    float*  pack   = (float*)(ws + 4 * MiB);
    float*  scfeat = (float*)(ws + 34 * MiB);
    ushort* wbev_s = (ushort*)(ws + 49 * MiB);
    ushort* wq_s   = wbev_s + 128 * 256;
    ushort* wout_s = wq_s   + 128 * 128;
    ushort* wfc1_s = wout_s + 128 * 128;
    ushort* wfc2_s = wfc1_s + 128 * 128;
    ushort* wkt_s  = wfc2_s + 128 * 128;

    hipMemsetAsync(inv, 0xFF, (size_t)4 * H_Y * W_X * sizeof(int), stream);
    build_inv<<<(M + 255) / 256, 256, 0, stream>>>(ni, inv, M);

    conv_swz<<<128, 256, 0, stream>>>(w_bev, wbev_s, C_BEV, 128 * 256);
    conv_swz<<<64, 256, 0, stream>>>(w_in,  wq_s,   C_IN, 128 * 128);
    conv_swz<<<64, 256, 0, stream>>>(w_out, wout_s, C_IN, 128 * 128);
    conv_swz<<<64, 256, 0, stream>>>(w_fc1, wfc1_s, C_IN, 128 * 128);
    conv_swz<<<64, 256, 0, stream>>>(w_fc2, wfc2_s, C_IN, 128 * 128);
    conv_swz_t<<<64, 256, 0, stream>>>(w_in, wkt_s);

    compact_bev<<<4 * H_Y * 12, 256, 0, stream>>>(bev, inv, pack);

    k_pre<<<(M + 15) / 16, 256, 0, stream>>>(pack, wbev_s, b_bev, g_q, be_q,
                                             wq_s, wkt_s, b_in, scfeat, tbvbuf, M);
    k_attn<<<(M + 1) / 2, 512, 0, stream>>>(vf, spi, ni, kidx, pack, tbvbuf,
                                            w_pos, b_pos, g_k, be_k, w_in, b_in, M);
    k_post<<<(M + 15) / 16, 256, 0, stream>>>(pack, wout_s, b_out, g_f, be_f,
                                              wfc1_s, b_fc1, wfc2_s, b_fc2, scfeat, M);

    write_out_t<<<4 * H_Y * 12, 256, 0, stream>>>(inv, scfeat, out);
}

// Round 25
// 327.862 us; speedup vs baseline: 5.2622x; 1.4085x over previous
//
#include <hip/hip_runtime.h>
#include <hip/hip_bf16.h>
#include <cmath>

#define C_IN 128
#define NKEY 32
#define N_H 4
#define D_H 32
#define C_BEV 256
#define H_Y 180
#define W_X 180

typedef __attribute__((ext_vector_type(8))) short short8;
typedef __attribute__((ext_vector_type(4))) float f32x4;

// tanh-form GELU via hw exp (verified R24): |err| < 4e-4, clamp avoids NaN.
__device__ __forceinline__ float gelu_fast(float x) {
    const float y2 = fminf(1.5957691216057308f * (x + 0.044715f * x * x * x), 80.0f);
    const float e = __expf(y2);
    return x * e / (e + 1.0f);
}
__device__ __forceinline__ float dot4(float4 a, float4 b) {
    return a.x * b.x + a.y * b.y + a.z * b.z + a.w * b.w;
}
__device__ __forceinline__ float bf2f(ushort u) {
    union { unsigned int i; float f; } c; c.i = ((unsigned int)u) << 16; return c.f;
}
__device__ __forceinline__ ushort f2bf(float x) {
    __hip_bfloat16 h = __float2bfloat16(x);
    return *reinterpret_cast<ushort*>(&h);
}

// ---- one-time: f32 weight [OUT][K] -> bf16 MFMA fragment order (verified R21)
__global__ void conv_swz(const float* __restrict__ src, ushort* __restrict__ dst,
                         int K, int total) {
    const int idx = blockIdx.x * 256 + threadIdx.x;
    if (idx < total) {
        const int j = idx & 7;
        const int t8 = idx >> 3;
        const int lane = t8 & 63;
        const int tile = t8 >> 6;
        const int NK = K >> 5;
        const int kt = tile % NK, ct = tile / NK;
        const int row = ct * 16 + (lane & 15);
        const int k = kt * 32 + (lane >> 4) * 8 + j;
        dst[idx] = f2bf(src[(size_t)row * K + k]);
    }
}

// ---- one-time: wk^T per head -> fragment order for t-GEMM (verified R23)
__global__ void conv_swz_t(const float* __restrict__ w_in, ushort* __restrict__ dst) {
    const int idx = blockIdx.x * 256 + threadIdx.x;   // 16384
    if (idx < 16384) {
        const int j = idx & 7;
        const int lane = (idx >> 3) & 63;
        const int tile = idx >> 9;
        const int ct = tile & 7, h = tile >> 3;
        const int row_w = 128 + h * 32 + (lane >> 4) * 8 + j;
        const int col = ct * 16 + (lane & 15);
        dst[idx] = f2bf(w_in[(size_t)row_w * C_IN + col]);
    }
}

// ---- inv[cell] = m  (inv pre-memset to -1)
__global__ void build_inv(const int* __restrict__ ni, int* __restrict__ inv, int M) {
    const int m = blockIdx.x * 256 + threadIdx.x;
    if (m < M) {
        const int b = ni[m*4+0], y = ni[m*4+2], x = ni[m*4+3];
        inv[(b * H_Y + y) * W_X + x] = m;
    }
}

// ---- compact bev -> pack[m][0:256] contiguous (verified R8/R13)
__global__ __launch_bounds__(256) void compact_bev(
    const float* __restrict__ bev, const int* __restrict__ inv,
    float* __restrict__ pack)
{
    const int bid = blockIdx.x;
    const int xr = bid % 12;
    const int y  = (bid / 12) % H_Y;
    const int b  = bid / (12 * H_Y);
    const int x0 = xr * 16;
    const int width = (x0 + 16 <= W_X) ? 16 : (W_X - x0);
    const int tid = threadIdx.x;

    __shared__ float tile[16][257];

    const int xq = (tid & 3) * 4;
    #pragma unroll
    for (int p = 0; p < 4; ++p) {
        const int c = p * 64 + (tid >> 2);
        if (xq < width) {
            const float4 v = *(const float4*)(bev +
                (((size_t)b * C_BEV + c) * H_Y + y) * W_X + x0 + xq);
            tile[xq+0][c] = v.x; tile[xq+1][c] = v.y;
            tile[xq+2][c] = v.z; tile[xq+3][c] = v.w;
        }
    }
    __syncthreads();
    for (int xi = 0; xi < width; ++xi) {
        const int m = inv[(b * H_Y + y) * W_X + x0 + xi];
        if (m >= 0) pack[(size_t)m * C_BEV + tid] = tile[xi][tid];
    }
}

// ---- transposed write-out (verified R19)
__global__ __launch_bounds__(256) void write_out_t(
    const int* __restrict__ inv, const float* __restrict__ featbuf,
    float* __restrict__ out)
{
    const int bid = blockIdx.x;
    const int xr = bid % 12;
    const int y  = (bid / 12) % H_Y;
    const int b  = bid / (12 * H_Y);
    const int x0 = xr * 16;
    const int width = (x0 + 16 <= W_X) ? 16 : (W_X - x0);
    const int tid = threadIdx.x;

    __shared__ float tile[16][C_IN + 1];
    __shared__ int m16[16];

    if (tid < 16) m16[tid] = (tid < width) ? inv[(b * H_Y + y) * W_X + x0 + tid] : -1;
    __syncthreads();

    #pragma unroll
    for (int pass = 0; pass < 8; ++pass) {
        const int xi = pass * 2 + (tid >> 7);
        const int c  = tid & 127;
        const int m  = m16[xi];
        tile[xi][c] = (m >= 0) ? featbuf[(size_t)m * C_IN + c] : 0.0f;
    }
    __syncthreads();

    #pragma unroll
    for (int pass = 0; pass < 8; ++pass) {
        const int c  = pass * 16 + (tid >> 4);
        const int xi = tid & 15;
        if (xi < width)
            out[(((size_t)b * C_IN + c) * H_Y + y) * W_X + x0 + xi] = tile[xi][c];
    }
}

// ---- MFMA pre-attention + t-precompute (verified R23/R24): 16 q / 256 threads.
__global__ __launch_bounds__(256) void k_pre(
    float* __restrict__ pack, const ushort* __restrict__ wbev_s,
    const float* __restrict__ b_bev, const float* __restrict__ g_q,
    const float* __restrict__ be_q, const ushort* __restrict__ wq_s,
    const ushort* __restrict__ wkt_s, const float* __restrict__ b_in,
    float* __restrict__ sc_g, float* __restrict__ tbvbuf, const int M)
{
    __shared__ ushort bevl16[16][C_BEV + 8];
    __shared__ float  scl[16][C_IN];
    __shared__ ushort qlnl16[16][C_IN + 8];
    __shared__ ushort qhl16[16][C_IN + 8];
    __shared__ ushort tl16[16][N_H][C_IN];
    const int tid = threadIdx.x;
    const int m16 = blockIdx.x * 16;
    const int wave = tid >> 6, lane = tid & 63;
    const int llo = lane & 15, lhi = lane >> 4;
    const int qs = tid >> 4, seg = tid & 15;
    int mq = m16 + qs; if (mq >= M) mq = M - 1;

    {
        const float4* srcp = (const float4*)(pack + (size_t)mq * C_BEV + seg * 16);
        ushort tmp[16];
        #pragma unroll
        for (int j4 = 0; j4 < 4; ++j4) {
            const float4 v = srcp[j4];
            tmp[j4*4+0] = f2bf(v.x); tmp[j4*4+1] = f2bf(v.y);
            tmp[j4*4+2] = f2bf(v.z); tmp[j4*4+3] = f2bf(v.w);
        }
        short8* d = (short8*)&bevl16[qs][seg * 16];
        d[0] = *(short8*)&tmp[0];
        d[1] = *(short8*)&tmp[8];
    }
    __syncthreads();                                  // B1

    {   // sc GEMM 16x128x256
        f32x4 acc0 = {0.f,0.f,0.f,0.f}, acc1 = {0.f,0.f,0.f,0.f};
        #pragma unroll
        for (int kt = 0; kt < 8; ++kt) {
            const short8 a = *(const short8*)&bevl16[llo][kt*32 + lhi*8];
            const short8 b0 = *(const short8*)&wbev_s[(size_t)(((wave    )*8 + kt)*64 + lane)*8];
            const short8 b1 = *(const short8*)&wbev_s[(size_t)(((wave + 4)*8 + kt)*64 + lane)*8];
            acc0 = __builtin_amdgcn_mfma_f32_16x16x32_bf16(a, b0, acc0, 0, 0, 0);
            acc1 = __builtin_amdgcn_mfma_f32_16x16x32_bf16(a, b1, acc1, 0, 0, 0);
        }
        #pragma unroll
        for (int qe = 0; qe < 4; ++qe) {
            const int row = lhi * 4 + qe;
            const int c0 = wave * 16 + llo, c1 = (wave + 4) * 16 + llo;
            scl[row][c0] = gelu_fast(acc0[qe] + b_bev[c0]);
            scl[row][c1] = gelu_fast(acc1[qe] + b_bev[c1]);
        }
    }
    __syncthreads();                                  // B2

    {   // sc_g write + LN -> qlnl16
        float* dst = sc_g + (size_t)mq * C_IN + seg * 8;
        float v[8];
        #pragma unroll
        for (int j = 0; j < 8; ++j) v[j] = scl[qs][seg * 8 + j];
        *(float4*)&dst[0] = make_float4(v[0], v[1], v[2], v[3]);
        *(float4*)&dst[4] = make_float4(v[4], v[5], v[6], v[7]);

        float s = 0.f;
        #pragma unroll
        for (int j = 0; j < 8; ++j) s += v[j];
        s += __shfl_xor(s, 1); s += __shfl_xor(s, 2);
        s += __shfl_xor(s, 4); s += __shfl_xor(s, 8);
        const float mean = s * (1.0f / 128.0f);
        float vv = 0.f;
        #pragma unroll
        for (int j = 0; j < 8; ++j) { const float d = v[j] - mean; vv += d * d; }
        vv += __shfl_xor(vv, 1); vv += __shfl_xor(vv, 2);
        vv += __shfl_xor(vv, 4); vv += __shfl_xor(vv, 8);
        const float rs = rsqrtf(vv * (1.0f / 128.0f) + 1e-5f);
        #pragma unroll
        for (int j = 0; j < 8; ++j) {
            const int c = seg * 8 + j;
            qlnl16[qs][c] = f2bf((v[j] - mean) * rs * g_q[c] + be_q[c]);
        }
    }
    __syncthreads();                                  // B3

    {   // qh GEMM 16x128x128 -> scl (f32) + qhl16 (bf16)
        f32x4 acc0 = {0.f,0.f,0.f,0.f}, acc1 = {0.f,0.f,0.f,0.f};
        #pragma unroll
        for (int kt = 0; kt < 4; ++kt) {
            const short8 a = *(const short8*)&qlnl16[llo][kt*32 + lhi*8];
            const short8 b0 = *(const short8*)&wq_s[(size_t)(((wave    )*4 + kt)*64 + lane)*8];
            const short8 b1 = *(const short8*)&wq_s[(size_t)(((wave + 4)*4 + kt)*64 + lane)*8];
            acc0 = __builtin_amdgcn_mfma_f32_16x16x32_bf16(a, b0, acc0, 0, 0, 0);
            acc1 = __builtin_amdgcn_mfma_f32_16x16x32_bf16(a, b1, acc1, 0, 0, 0);
        }
        #pragma unroll
        for (int qe = 0; qe < 4; ++qe) {
            const int row = lhi * 4 + qe;
            const int c0 = wave * 16 + llo, c1 = (wave + 4) * 16 + llo;
            const float v0 = acc0[qe] + b_in[c0];
            const float v1 = acc1[qe] + b_in[c1];
            scl[row][c0] = v0;  qhl16[row][c0] = f2bf(v0);
            scl[row][c1] = v1;  qhl16[row][c1] = f2bf(v1);
        }
    }
    __syncthreads();                                  // B4

    {   // t GEMM: per head K=32
        #pragma unroll
        for (int h = 0; h < N_H; ++h) {
            const short8 a = *(const short8*)&qhl16[llo][h*32 + lhi*8];
            #pragma unroll
            for (int cti = 0; cti < 2; ++cti) {
                const int ct = wave + cti * 4;
                const short8 b = *(const short8*)&wkt_s[(size_t)(((h*8 + ct)*64 + lane))*8];
                f32x4 acc = {0.f,0.f,0.f,0.f};
                acc = __builtin_amdgcn_mfma_f32_16x16x32_bf16(a, b, acc, 0, 0, 0);
                #pragma unroll
                for (int qe = 0; qe < 4; ++qe)
                    tl16[lhi*4 + qe][h][ct*16 + llo] = f2bf(acc[qe]);
            }
        }
    }
    __syncthreads();                                  // B5

    {   // t -> pack row + tbv
        ushort* dstu = (ushort*)(pack + (size_t)mq * C_BEV);
        const ushort* srcu = &tl16[qs][0][0];
        #pragma unroll
        for (int j8 = 0; j8 < 4; ++j8)
            *(short8*)&dstu[seg*32 + j8*8] = *(const short8*)&srcu[seg*32 + j8*8];

        const int h = seg >> 2, quarter = seg & 3;
        float part = 0.f;
        #pragma unroll
        for (int j = 0; j < 8; ++j) {
            const int d = h*32 + quarter*8 + j;
            part += scl[qs][d] * b_in[C_IN + d];
        }
        part += __shfl_xor(part, 1);
        part += __shfl_xor(part, 2);
        if (quarter == 0) tbvbuf[(size_t)mq * 4 + h] = part;
    }
}

// ---- attention kernel: 2q/512t. logits + av on MFMA; kbar VALU->bf16.
__global__ __launch_bounds__(512) void k_attn(
    const float* __restrict__ vf, const int* __restrict__ spi,
    const int* __restrict__ ni, const int* __restrict__ kidx,
    float* __restrict__ pack, const float* __restrict__ tbvbuf,
    const float* __restrict__ w_pos, const float* __restrict__ b_pos,
    const float* __restrict__ g_k, const float* __restrict__ be_k,
    const ushort* __restrict__ wv_s, const float* __restrict__ b_in,
    const int M)
{
    const int tid = threadIdx.x;
    const int m2 = blockIdx.x * 2;
    const int mA = m2;
    const int mB = (m2 + 1 < M) ? (m2 + 1) : (M - 1);

    __shared__ ushort kf16[64][C_IN + 8];
    __shared__ ushort t16[2][N_H][C_IN + 8];   // t bf16 (B for logits GEMM)
    __shared__ float  Sl[2][NKEY][4];          // logits
    __shared__ float  attnw[2 * 4 * NKEY];
    __shared__ ushort kbarA16[16][C_IN + 8];   // kbar bf16 (A for av GEMM)
    __shared__ float  tbvs[8];
    __shared__ int    kmsk[64];
    __shared__ int    kvs[64];
    __shared__ int    lst[64];
    __shared__ int    cntS;
    __shared__ float  prm[768];

    const int wave = tid >> 6, lane = tid & 63;
    const int llo = lane & 15, lhi = lane >> 4;
    const int nxA = ni[mA*4+3], nyA = ni[mA*4+2];
    const int nxB = ni[mB*4+3], nyB = ni[mB*4+2];

    for (int i = tid; i < 768; i += 512) {
        float val;
        if (i < 384)      val = w_pos[i];
        else if (i < 512) val = b_pos[i - 384];
        else if (i < 640) val = g_k[i - 512];
        else              val = be_k[i - 640];
        prm[i] = val;
    }
    {   // stage t (bf16, h-major rows, padded)
        const int q = tid >> 8, rem = tid & 255;
        const int h = rem >> 6, c2 = rem & 63;
        const uint u = ((const uint*)(pack + (size_t)(q ? mB : mA) * C_BEV))[rem];
        ((uint*)&t16[q][h][0])[c2] = u;
    }
    if (tid < 8) tbvs[tid] = tbvbuf[(size_t)((tid >> 2) ? mB : mA) * 4 + (tid & 3)];
    if (tid < 64) {
        const int qk = tid >> 5;
        const int kv = kidx[(size_t)(qk ? mB : mA) * NKEY + (tid & 31)];
        const bool act = (kv >= 0);
        kmsk[tid] = act ? 0 : 1;
        kvs[tid]  = act ? kv : 0;
        const unsigned long long bal = __ballot(act);
        if (tid == 0) cntS = (int)__popcll(bal);
        if (act) lst[(int)__popcll(bal & ((1ull << tid) - 1ull))] = tid;
    }
    __syncthreads();                                  // B1

    {   // P1: zero masked rows; gather+posemb+LN for active rows (verified R22/R24)
        const int grp = tid >> 3, g = tid & 7, c0 = g * 16;
        if (kmsk[grp]) {
            const short8 z = (short8){0,0,0,0,0,0,0,0};
            short8* d = (short8*)&kf16[grp][c0];
            d[0] = z; d[1] = z;
        }
        if (grp < cntS) {
            const int kk = lst[grp];
            const int qk = kk >> 5;
            const int safe = kvs[kk];
            const int nxk = qk ? nxB : nxA, nyk = qk ? nyB : nyA;
            const float qxk = (nxk + 0.5f) * (150.4f / 180.0f) - 75.2f;
            const float qyk = (nyk + 0.5f) * (150.4f / 180.0f) - 75.2f;
            const int sz = spi[safe * 4 + 1];
            const int sy = spi[safe * 4 + 2];
            const int sx = spi[safe * 4 + 3];
            const float cx = (sx + 0.5f) * (150.4f / 1440.0f) - 75.2f - qxk;
            const float cy = (sy + 0.5f) * (150.4f / 1440.0f) - 75.2f - qyk;
            const float cz = (sz + 0.5f) * (6.0f / 40.0f)     - 3.0f;

            float v[16];
            const float4* src = (const float4*)(vf + (size_t)safe * C_IN + c0);
            #pragma unroll
            for (int j = 0; j < 4; ++j) {
                float4 t = src[j];
                v[j*4+0] = t.x; v[j*4+1] = t.y; v[j*4+2] = t.z; v[j*4+3] = t.w;
            }
            #pragma unroll
            for (int ch = 0; ch < 2; ++ch) {
                const int cb = c0 + ch * 8;
                float wpl[24];
                const float4* wpr = (const float4*)&prm[cb * 3];
                #pragma unroll
                for (int j4 = 0; j4 < 6; ++j4) *(float4*)&wpl[j4*4] = wpr[j4];
                float bpl[8];
                *(float4*)&bpl[0] = *(const float4*)&prm[384 + cb];
                *(float4*)&bpl[4] = *(const float4*)&prm[384 + cb + 4];
                #pragma unroll
                for (int j = 0; j < 8; ++j) {
                    const float e = cx*wpl[j*3+0] + cy*wpl[j*3+1] + cz*wpl[j*3+2] + bpl[j];
                    v[ch*8+j] += gelu_fast(e);
                }
            }
            float s = 0.f;
            #pragma unroll
            for (int j = 0; j < 16; ++j) s += v[j];
            s += __shfl_xor(s, 1); s += __shfl_xor(s, 2); s += __shfl_xor(s, 4);
            const float mean = s * (1.0f / 128.0f);
            float vv = 0.f;
            #pragma unroll
            for (int j = 0; j < 16; ++j) { const float d = v[j] - mean; vv += d * d; }
            vv += __shfl_xor(vv, 1); vv += __shfl_xor(vv, 2); vv += __shfl_xor(vv, 4);
            const float rs = rsqrtf(vv * (1.0f / 128.0f) + 1e-5f);
            ushort o[16];
            #pragma unroll
            for (int ch = 0; ch < 2; ++ch) {
                const int cb = c0 + ch * 8;
                float gkl[8], bel[8];
                *(float4*)&gkl[0] = *(const float4*)&prm[512 + cb];
                *(float4*)&gkl[4] = *(const float4*)&prm[512 + cb + 4];
                *(float4*)&bel[0] = *(const float4*)&prm[640 + cb];
                *(float4*)&bel[4] = *(const float4*)&prm[640 + cb + 4];
                #pragma unroll
                for (int j = 0; j < 8; ++j)
                    o[ch*8+j] = f2bf((v[ch*8+j] - mean) * rs * gkl[j] + bel[j]);
            }
            short8* drow = (short8*)(&kf16[kk][c0]);
            drow[0] = *(short8*)&o[0];
            drow[1] = *(short8*)&o[8];
        }
    }
    __syncthreads();                                  // B2

    // logits MFMA (waves 0-3): per (q,rt): S[32x4] = kf16 @ t^T  (K=128)
    if (wave < 4) {
        const int q = wave >> 1, rt = wave & 1;
        f32x4 acc = {0.f,0.f,0.f,0.f};
        #pragma unroll
        for (int kt = 0; kt < 4; ++kt) {
            const short8 a = *(const short8*)&kf16[q*NKEY + rt*16 + llo][kt*32 + lhi*8];
            const short8 b = *(const short8*)&t16[q][llo & 3][kt*32 + lhi*8];
            acc = __builtin_amdgcn_mfma_f32_16x16x32_bf16(a, b, acc, 0, 0, 0);
        }
        if (llo < 4) {
            #pragma unroll
            for (int qe = 0; qe < 4; ++qe)
                Sl[q][rt*16 + lhi*4 + qe][llo] = acc[qe];
        }
    } else {
        // zero kbarA16 rows 8..15 (A rows never written by kbar; avoid NaN reads)
        const int idx = (wave - 4) * 64 + lane;       // 0..255
        uint* zb = (uint*)&kbarA16[8][0];             // 8*(136) ushorts = 544 uints? no: 8*136/2=544
        if (idx < 544) zb[idx] = 0;
        if (idx + 256 < 544) zb[idx + 256] = 0;
    }
    __syncthreads();                                  // B3

    // softmax (tid<256): read Sl, write attnw f32
    if (tid < 256) {
        const int q = tid >> 7, h = (tid >> 5) & 3, p = tid & 31;
        const int msk = kmsk[q*NKEY + p];
        float logit = msk ? -3.0e38f
                          : (Sl[q][p][h] + tbvs[q*4 + h]) * 0.17677669529663687f;
        float mx = logit;
        #pragma unroll
        for (int o = 16; o >= 1; o >>= 1) mx = fmaxf(mx, __shfl_xor(mx, o));
        const float e = msk ? 0.0f : __expf(logit - mx);
        float ssum = e;
        #pragma unroll
        for (int o = 16; o >= 1; o >>= 1) ssum += __shfl_xor(ssum, o);
        attnw[(q*4 + h)*32 + p] = e / ssum;
    }
    __syncthreads();                                  // B4

    // kbar (VALU) -> kbarA16 bf16, rows m = q*4+h
    {
        const int q = tid >> 8, r = tid & 255;
        const int c = r & 127, h2 = r >> 7;
        #pragma unroll
        for (int hi = 0; hi < 2; ++hi) {
            const int hh = h2 + 2 * hi;
            float acc = 0.f;
            #pragma unroll
            for (int p = 0; p < NKEY; ++p)
                acc += attnw[(q*4 + hh)*32 + p] * bf2f(kf16[q*NKEY + p][c]);
            kbarA16[q*4 + hh][c] = f2bf(acc);
        }
    }
    __syncthreads();                                  // B5

    // av MFMA: out[m=q*4+h][j] = kbar @ wv^T; wave = ct
    {
        const int ct = wave;
        const int h = ct >> 1;
        f32x4 acc = {0.f,0.f,0.f,0.f};
        #pragma unroll
        for (int kt = 0; kt < 4; ++kt) {
            const short8 a = *(const short8*)&kbarA16[llo][kt*32 + lhi*8];
            const short8 b = *(const short8*)&wv_s[(size_t)(((ct*4 + kt)*64 + lane))*8];
            acc = __builtin_amdgcn_mfma_f32_16x16x32_bf16(a, b, acc, 0, 0, 0);
        }
        if (lhi < 2) {
            const int q = lhi;
            const int j = ct * 16 + llo;
            if ((m2 + q) < M)
                pack[(size_t)(q ? mB : mA) * C_BEV + C_IN + j] = acc[h] + b_in[2*C_IN + j];
        }
    }
}

// ---- MFMA post-attention (verified R21/R24): 16 queries / 256-thread block.
__global__ __launch_bounds__(256) void k_post(
    const float* __restrict__ pack,
    const ushort* __restrict__ wout_s, const float* __restrict__ b_out,
    const float* __restrict__ g_f, const float* __restrict__ be_f,
    const ushort* __restrict__ wfc1_s, const float* __restrict__ b_fc1,
    const ushort* __restrict__ wfc2_s, const float* __restrict__ b_fc2,
    float* __restrict__ scfeat, const int M)
{
    __shared__ ushort avl16[16][C_IN + 8];
    __shared__ float  sclp[16][C_IN];
    __shared__ float  xfl[16][C_IN];
    __shared__ ushort ylnl16[16][C_IN + 8];
    __shared__ ushort h1l16[16][C_IN + 8];
    const int tid = threadIdx.x;
    const int m16 = blockIdx.x * 16;
    const int wave = tid >> 6, lane = tid & 63;
    const int llo = lane & 15, lhi = lane >> 4;
    const int qs = tid >> 4, seg = tid & 15;
    int mq = m16 + qs; if (mq >= M) mq = M - 1;

    {
        const float4* ap = (const float4*)(pack + (size_t)mq * C_BEV + C_IN + seg * 8);
        const float4 a0 = ap[0], a1 = ap[1];
        ushort tmp[8];
        tmp[0]=f2bf(a0.x); tmp[1]=f2bf(a0.y); tmp[2]=f2bf(a0.z); tmp[3]=f2bf(a0.w);
        tmp[4]=f2bf(a1.x); tmp[5]=f2bf(a1.y); tmp[6]=f2bf(a1.z); tmp[7]=f2bf(a1.w);
        *(short8*)&avl16[qs][seg * 8] = *(short8*)&tmp[0];
        const float4* sp = (const float4*)(scfeat + (size_t)mq * C_IN + seg * 8);
        *(float4*)&sclp[qs][seg * 8]     = sp[0];
        *(float4*)&sclp[qs][seg * 8 + 4] = sp[1];
    }
    __syncthreads();

    {
        f32x4 acc0 = {0.f,0.f,0.f,0.f}, acc1 = {0.f,0.f,0.f,0.f};
        #pragma unroll
        for (int kt = 0; kt < 4; ++kt) {
            const short8 a = *(const short8*)&avl16[llo][kt*32 + lhi*8];
            const short8 b0 = *(const short8*)&wout_s[(size_t)(((wave    )*4 + kt)*64 + lane)*8];
            const short8 b1 = *(const short8*)&wout_s[(size_t)(((wave + 4)*4 + kt)*64 + lane)*8];
            acc0 = __builtin_amdgcn_mfma_f32_16x16x32_bf16(a, b0, acc0, 0, 0, 0);
            acc1 = __builtin_amdgcn_mfma_f32_16x16x32_bf16(a, b1, acc1, 0, 0, 0);
        }
        #pragma unroll
        for (int qe = 0; qe < 4; ++qe) {
            const int row = lhi * 4 + qe;
            const int c0 = wave * 16 + llo, c1 = (wave + 4) * 16 + llo;
            xfl[row][c0] = acc0[qe] + b_out[c0] + sclp[row][c0];
            xfl[row][c1] = acc1[qe] + b_out[c1] + sclp[row][c1];
        }
    }
    __syncthreads();

    {
        float v[8];
        #pragma unroll
        for (int j = 0; j < 8; ++j) v[j] = xfl[qs][seg * 8 + j];
        float s = 0.f;
        #pragma unroll
        for (int j = 0; j < 8; ++j) s += v[j];
        s += __shfl_xor(s, 1); s += __shfl_xor(s, 2);
        s += __shfl_xor(s, 4); s += __shfl_xor(s, 8);
        const float mean = s * (1.0f / 128.0f);
        float vv = 0.f;
        #pragma unroll
        for (int j = 0; j < 8; ++j) { const float d = v[j] - mean; vv += d * d; }
        vv += __shfl_xor(vv, 1); vv += __shfl_xor(vv, 2);
        vv += __shfl_xor(vv, 4); vv += __shfl_xor(vv, 8);
        const float rs = rsqrtf(vv * (1.0f / 128.0f) + 1e-5f);
        #pragma unroll
        for (int j = 0; j < 8; ++j) {
            const int c = seg * 8 + j;
            ylnl16[qs][c] = f2bf((v[j] - mean) * rs * g_f[c] + be_f[c]);
        }
    }
    __syncthreads();

    {
        f32x4 acc0 = {0.f,0.f,0.f,0.f}, acc1 = {0.f,0.f,0.f,0.f};
        #pragma unroll
        for (int kt = 0; kt < 4; ++kt) {
            const short8 a = *(const short8*)&ylnl16[llo][kt*32 + lhi*8];
            const short8 b0 = *(const short8*)&wfc1_s[(size_t)(((wave    )*4 + kt)*64 + lane)*8];
            const short8 b1 = *(const short8*)&wfc1_s[(size_t)(((wave + 4)*4 + kt)*64 + lane)*8];
            acc0 = __builtin_amdgcn_mfma_f32_16x16x32_bf16(a, b0, acc0, 0, 0, 0);
            acc1 = __builtin_amdgcn_mfma_f32_16x16x32_bf16(a, b1, acc1, 0, 0, 0);
        }
        #pragma unroll
        for (int qe = 0; qe < 4; ++qe) {
            const int row = lhi * 4 + qe;
            const int c0 = wave * 16 + llo, c1 = (wave + 4) * 16 + llo;
            h1l16[row][c0] = f2bf(gelu_fast(acc0[qe] + b_fc1[c0]));
            h1l16[row][c1] = f2bf(gelu_fast(acc1[qe] + b_fc1[c1]));
        }
    }
    __syncthreads();

    {
        f32x4 acc0 = {0.f,0.f,0.f,0.f}, acc1 = {0.f,0.f,0.f,0.f};
        #pragma unroll
        for (int kt = 0; kt < 4; ++kt) {
            const short8 a = *(const short8*)&h1l16[llo][kt*32 + lhi*8];
            const short8 b0 = *(const short8*)&wfc2_s[(size_t)(((wave    )*4 + kt)*64 + lane)*8];
            const short8 b1 = *(const short8*)&wfc2_s[(size_t)(((wave + 4)*4 + kt)*64 + lane)*8];
            acc0 = __builtin_amdgcn_mfma_f32_16x16x32_bf16(a, b0, acc0, 0, 0, 0);
            acc1 = __builtin_amdgcn_mfma_f32_16x16x32_bf16(a, b1, acc1, 0, 0, 0);
        }
        #pragma unroll
        for (int qe = 0; qe < 4; ++qe) {
            const int row = lhi * 4 + qe;
            const int c0 = wave * 16 + llo, c1 = (wave + 4) * 16 + llo;
            sclp[row][c0] = acc0[qe] + b_fc2[c0] + xfl[row][c0];
            sclp[row][c1] = acc1[qe] + b_fc2[c1] + xfl[row][c1];
        }
    }
    __syncthreads();

    {
        float* dst = scfeat + (size_t)mq * C_IN + seg * 8;
        *(float4*)&dst[0] = make_float4(sclp[qs][seg*8+0], sclp[qs][seg*8+1],
                                        sclp[qs][seg*8+2], sclp[qs][seg*8+3]);
        *(float4*)&dst[4] = make_float4(sclp[qs][seg*8+4], sclp[qs][seg*8+5],
                                        sclp[qs][seg*8+6], sclp[qs][seg*8+7]);
    }
}

extern "C" void kernel_launch(void* const* d_in, const int* in_sizes, int n_in,
                              void* d_out, int out_size, void* d_ws, size_t ws_size,
                              hipStream_t stream) {
    const float* vf    = (const float*)d_in[0];
    const int*   spi   = (const int*)  d_in[1];
    const int*   ni    = (const int*)  d_in[2];
    const int*   kidx  = (const int*)  d_in[3];
    const float* bev   = (const float*)d_in[4];
    const float* w_pos = (const float*)d_in[5];
    const float* b_pos = (const float*)d_in[6];
    const float* w_bev = (const float*)d_in[7];
    const float* b_bev = (const float*)d_in[8];
    const float* g_q   = (const float*)d_in[9];
    const float* be_q  = (const float*)d_in[10];
    const float* g_k   = (const float*)d_in[11];
    const float* be_k  = (const float*)d_in[12];
    const float* g_f   = (const float*)d_in[13];
    const float* be_f  = (const float*)d_in[14];
    const float* w_in  = (const float*)d_in[15];
    const float* b_in  = (const float*)d_in[16];
    const float* w_out = (const float*)d_in[17];
    const float* b_out = (const float*)d_in[18];
    const float* w_fc1 = (const float*)d_in[19];
    const float* b_fc1 = (const float*)d_in[20];
    const float* w_fc2 = (const float*)d_in[21];
    const float* b_fc2 = (const float*)d_in[22];
    float* out = (float*)d_out;

    const int M = in_sizes[3] / NKEY;

    char* ws = (char*)d_ws;
    const size_t MiB = 1u << 20;
    int*    inv    = (int*)ws;
    float*  tbvbuf = (float*)(ws + 2 * MiB);
    float*  pack   = (float*)(ws + 4 * MiB);
    float*  scfeat = (float*)(ws + 34 * MiB);
    ushort* wbev_s = (ushort*)(ws + 49 * MiB);
    ushort* wq_s   = wbev_s + 128 * 256;
    ushort* wout_s = wq_s   + 128 * 128;
    ushort* wfc1_s = wout_s + 128 * 128;
    ushort* wfc2_s = wfc1_s + 128 * 128;
    ushort* wkt_s  = wfc2_s + 128 * 128;
    ushort* wv_s   = wkt_s  + 16384;

    hipMemsetAsync(inv, 0xFF, (size_t)4 * H_Y * W_X * sizeof(int), stream);
    build_inv<<<(M + 255) / 256, 256, 0, stream>>>(ni, inv, M);

    conv_swz<<<128, 256, 0, stream>>>(w_bev, wbev_s, C_BEV, 128 * 256);
    conv_swz<<<64, 256, 0, stream>>>(w_in,  wq_s,   C_IN, 128 * 128);
    conv_swz<<<64, 256, 0, stream>>>(w_out, wout_s, C_IN, 128 * 128);
    conv_swz<<<64, 256, 0, stream>>>(w_fc1, wfc1_s, C_IN, 128 * 128);
    conv_swz<<<64, 256, 0, stream>>>(w_fc2, wfc2_s, C_IN, 128 * 128);
    conv_swz_t<<<64, 256, 0, stream>>>(w_in, wkt_s);
    conv_swz<<<64, 256, 0, stream>>>(w_in + 2 * C_IN * C_IN, wv_s, C_IN, 128 * 128);

    compact_bev<<<4 * H_Y * 12, 256, 0, stream>>>(bev, inv, pack);

    k_pre<<<(M + 15) / 16, 256, 0, stream>>>(pack, wbev_s, b_bev, g_q, be_q,
                                             wq_s, wkt_s, b_in, scfeat, tbvbuf, M);
    k_attn<<<(M + 1) / 2, 512, 0, stream>>>(vf, spi, ni, kidx, pack, tbvbuf,
                                            w_pos, b_pos, g_k, be_k, wv_s, b_in, M);
    k_post<<<(M + 15) / 16, 256, 0, stream>>>(pack, wout_s, b_out, g_f, be_f,
                                              wfc1_s, b_fc1, wfc2_s, b_fc2, scfeat, M);

    write_out_t<<<4 * H_Y * 12, 256, 0, stream>>>(inv, scfeat, out);
}